// Round 1
// baseline (8968.803 us; speedup 1.0000x reference)
//
#include <hip/hip_runtime.h>
#include <hip/hip_cooperative_groups.h>

namespace cg = cooperative_groups;

#define N_TRAIN   2048
#define DOUT      16
#define DACT      8
#define DIN       24
#define HORIZON   64
#define JITTER    1e-6f

#define NBLK      256
#define NTHR      512
#define RPB       8        // rows (training points) per block: 2048/256
#define KLS       2052     // kl LDS stride in bf16 elems (padded: bank-conflict-free)
#define CPT       64       // columns per thread within a 32-thread jg-group: 2048/32

#define POWER_ITERS 8
#define RICH_ITERS  16

// workspace offsets (in floats)
#define OFF_PV0   4194304              // after sq[2048*2048]
#define OFF_PV1   (OFF_PV0 + 32768)
#define OFF_AA0   (OFF_PV1 + 32768)
#define OFF_AA1   (OFF_AA0 + 32768)
#define OFF_AL    (OFF_AA1 + 32768)
#define OFF_PART  (OFF_AL  + 32768)    // 2 * NBLK * 128 floats
// total = 4194304 + 5*32768 + 65536 = 4,423,680 floats = 17.7 MB

__device__ __forceinline__ float fexp2(float x){ return __builtin_amdgcn_exp2f(x); }

__device__ __forceinline__ float bf2f(unsigned short u){
  union { unsigned int i; float f; } v; v.i = ((unsigned int)u) << 16; return v.f;
}
__device__ __forceinline__ unsigned short f2bf(float f){
  union { float f; unsigned int i; } v; v.f = f;
  unsigned int r = v.i + 0x7fffu + ((v.i >> 16) & 1u);
  return (unsigned short)(r >> 16);
}

// Computes, for this block's 8 rows and all 16 outputs:
//   wfin[r*16+d] = g_d * ( sum_j exp2(ce_d * sq[row,j]) * u_d[j]  -  u_d[row] )
// i.e. w = G_d * u_d restricted to this block's rows (G = (var/s)*offdiag(C)).
// MODE 0: u from global V, layout [d][2048].  MODE 1: u from LDS kl (bf16).
template<int MODE>
__device__ __forceinline__ void sweep_block(
    const float* __restrict__ sq, const float* __restrict__ V,
    const unsigned short* kl, const float* ce_s, const float* g_s,
    float* wfin, int rowbase, int tid)
{
  const int d  = tid >> 5;   // 0..15 (half-wave uniform)
  const int jg = tid & 31;   // 0..31
  const float ced = ce_s[d];
  float acc[RPB];
#pragma unroll
  for (int r = 0; r < RPB; ++r) acc[r] = 0.f;
  const float* sq0 = sq + (size_t)rowbase * N_TRAIN;
#pragma unroll 2
  for (int t = 0; t < CPT; ++t){
    const int j = jg + (t << 5);
    float u;
    if (MODE == 0) u = V[d * N_TRAIN + j];
    else           u = bf2f(kl[d * KLS + j]);
#pragma unroll
    for (int r = 0; r < RPB; ++r){
      acc[r] = fmaf(fexp2(ced * sq0[r * N_TRAIN + j]), u, acc[r]);
    }
  }
  // reduce over the 32 jg lanes (within half-wave; masks <32 never cross halves)
#pragma unroll
  for (int r = 0; r < RPB; ++r){
    acc[r] += __shfl_xor(acc[r], 1);
    acc[r] += __shfl_xor(acc[r], 2);
    acc[r] += __shfl_xor(acc[r], 4);
    acc[r] += __shfl_xor(acc[r], 8);
    acc[r] += __shfl_xor(acc[r], 16);
  }
  if (jg == 0){
    const float gd = g_s[d];
#pragma unroll
    for (int r = 0; r < RPB; ++r){
      const int rowg = rowbase + r;
      float udiag;
      if (MODE == 0) udiag = V[d * N_TRAIN + rowg];
      else           udiag = bf2f(kl[d * KLS + rowg]);
      wfin[r * 16 + d] = gd * (acc[r] - udiag);
    }
  }
  __syncthreads();
}

__global__ __launch_bounds__(NTHR, 1)
void gp_rollout_kernel(const float* __restrict__ xtr, const float* __restrict__ ytr,
                       const float* __restrict__ ls,  const float* __restrict__ var,
                       const float* __restrict__ noi, const float* __restrict__ st0,
                       const float* __restrict__ act, const float* __restrict__ eps,
                       float* __restrict__ out, float* __restrict__ ws)
{
  cg::grid_group grid = cg::this_grid();
  const int tid = threadIdx.x;
  const int bid = blockIdx.x;
  const int rowbase = bid * RPB;

  float* sq   = ws;
  float* PV0  = ws + OFF_PV0;
  float* PV1  = ws + OFF_PV1;
  float* AA0  = ws + OFF_AA0;
  float* AA1  = ws + OFF_AA1;
  float* ALPH = ws + OFF_AL;
  float* PART = ws + OFF_PART;

  __shared__ float d2f[N_TRAIN];            // 8 KB (also reused as xrows in phase 0)
  __shared__ unsigned short kl[DOUT * KLS]; // 65.7 KB, bf16 kxs per output
  __shared__ float xcur[DIN];
  __shared__ float wfin[RPB * 16];
  __shared__ float pr[512];
  __shared__ float dsum[128];
  __shared__ float ce_s[16], g_s[16], s_s[16], var_s[16], nv_s[16];
  __shared__ float un_s[16], lam_s[16], sig_s[16], cb_s[16], ca_s[16];

  if (tid < 16){
    float l2 = ls[tid] * ls[tid];
    float nv = noi[tid] * noi[tid];
    float sd = var[tid] + nv + JITTER;
    ce_s[tid]  = -0.72134752044448f / l2;   // -0.5*log2(e)/ls^2  (exp -> exp2)
    g_s[tid]   = var[tid] / sd;
    s_s[tid]   = sd;
    var_s[tid] = var[tid];
    nv_s[tid]  = nv;
    un_s[tid]  = (float)N_TRAIN;            // ||ones||^2
  }
  __syncthreads();

  // ---------------- Phase 0: pairwise sq rows for this block; PV0 = ones ----
  {
    float* xrows = d2f;  // reuse LDS
    if (tid < RPB * DIN){
      int r = tid / DIN, k = tid % DIN;
      xrows[r * DIN + k] = xtr[(rowbase + r) * DIN + k];
    }
    __syncthreads();
    const int r = tid >> 6;       // 8 row-groups, one wave each
    const int lane = tid & 63;
    float xl[DIN];
#pragma unroll
    for (int k = 0; k < DIN; ++k) xl[k] = xrows[r * DIN + k];
    float* sqr = sq + (size_t)(rowbase + r) * N_TRAIN;
    for (int t = 0; t < 32; ++t){
      int j = lane + (t << 6);
      const float* xc = xtr + j * DIN;
      float sacc = 0.f;
#pragma unroll
      for (int k = 0; k < DIN; ++k){ float dd = xl[k] - xc[k]; sacc = fmaf(dd, dd, sacc); }
      sqr[j] = sacc;
    }
    if (tid < RPB * 16){
      int dd = tid >> 3, r2 = tid & 7;
      PV0[dd * N_TRAIN + rowbase + r2] = 1.0f;
    }
    __syncthreads();
  }
  __threadfence();
  grid.sync();
  int pc = 1;

  // ---------------- Power iteration: dominant eigenpair (lam, v1) of G ------
  float* PVc = PV0; float* PVn = PV1;
#pragma unroll 1
  for (int it = 0; it < POWER_ITERS; ++it){
    const bool last = (it == POWER_ITERS - 1);
    sweep_block<0>(sq, PVc, kl, ce_s, g_s, wfin, rowbase, tid);
    if (tid < 128){
      const int dd = tid >> 3, r = tid & 7;
      const int rowg = rowbase + r;
      float w = wfin[r * 16 + dd];
      PVn[dd * N_TRAIN + rowg] = w;
      float u = PVc[dd * N_TRAIN + rowg];
      pr[0 * 128 + tid] = w * w;
      pr[1 * 128 + tid] = u * w;
      pr[2 * 128 + tid] = last ? (ytr[rowg * 16 + dd] / s_s[dd]) * w : 0.f;
    }
    __syncthreads();
    if (tid < 48){
      const int slot = tid >> 4, dd = tid & 15;
      float s = 0.f;
#pragma unroll
      for (int r = 0; r < 8; ++r) s += pr[slot * 128 + dd * 8 + r];
      PART[(pc & 1) * (NBLK * 128) + bid * 128 + dd * 6 + slot] = s;
    }
    __threadfence();
    grid.sync();
    {
      const float* Pb = PART + (pc & 1) * (NBLK * 128);
      float s = 0.f;
      const int sidx = tid & 127, g2 = tid >> 7;
      for (int b = g2; b < NBLK; b += 4) s += Pb[b * 128 + sidx];
      pr[tid] = s;
      __syncthreads();
      if (tid < 96) dsum[tid] = pr[tid] + pr[128 + tid] + pr[256 + tid] + pr[384 + tid];
      __syncthreads();
    }
    if (tid < 16){
      float ww = dsum[tid * 6 + 0];
      float uw = dsum[tid * 6 + 1];
      if (last){
        lam_s[tid] = uw / fmaxf(un_s[tid], 1e-30f);  // Rayleigh quotient
        float sg = rsqrtf(fmaxf(ww, 1e-38f));
        sig_s[tid] = sg;                              // v1 = sig * PV (unit)
        cb_s[tid]  = sg * dsum[tid * 6 + 2];          // v1^T (y/s)
      }
      un_s[tid] = ww;
    }
    __syncthreads();
    ++pc;
    float* tmp = PVc; PVc = PVn; PVn = tmp;
  }

  // ---------------- a0 = b - cb*v1  (start of deflated Richardson) ----------
  {
    if (tid < 128){
      const int dd = tid >> 3, r = tid & 7;
      const int rowg = rowbase + r;
      float v = sig_s[dd] * PVc[dd * N_TRAIN + rowg];
      float b = ytr[rowg * 16 + dd] / s_s[dd];
      float a0 = b - cb_s[dd] * v;
      AA0[dd * N_TRAIN + rowg] = a0;
      pr[tid] = v * a0;
    }
    __syncthreads();
    if (tid < 16){
      float s = 0.f;
#pragma unroll
      for (int r = 0; r < 8; ++r) s += pr[tid * 8 + r];
      PART[(pc & 1) * (NBLK * 128) + bid * 128 + tid * 6 + 0] = s;
    }
    __threadfence();
    grid.sync();
    {
      const float* Pb = PART + (pc & 1) * (NBLK * 128);
      float s = 0.f;
      const int sidx = tid & 127, g2 = tid >> 7;
      for (int b = g2; b < NBLK; b += 4) s += Pb[b * 128 + sidx];
      pr[tid] = s;
      __syncthreads();
      if (tid < 96) dsum[tid] = pr[tid] + pr[128 + tid] + pr[256 + tid] + pr[384 + tid];
      __syncthreads();
    }
    if (tid < 16) ca_s[tid] = dsum[tid * 6 + 0];
    __syncthreads();
    ++pc;
  }

  // ---------------- Richardson on deflated operator: alpha = Ky^{-1} y ------
  float* Ac = AA0; float* An = AA1;
#pragma unroll 1
  for (int it = 0; it < RICH_ITERS; ++it){
    const bool last = (it == RICH_ITERS - 1);
    sweep_block<0>(sq, Ac, kl, ce_s, g_s, wfin, rowbase, tid);
    if (tid < 128){
      const int dd = tid >> 3, r = tid & 7;
      const int rowg = rowbase + r;
      float w = wfin[r * 16 + dd];                       // (G a)_row
      float v = sig_s[dd] * PVc[dd * N_TRAIN + rowg];
      float b = ytr[rowg * 16 + dd] / s_s[dd];
      float bperp = b - cb_s[dd] * v;
      float anew = bperp - (w - lam_s[dd] * ca_s[dd] * v);  // b_perp - Gtilde a
      float aout = last ? (anew + (cb_s[dd] / (1.f + lam_s[dd])) * v) : anew;
      float* dst = last ? ALPH : An;
      dst[dd * N_TRAIN + rowg] = aout;
      pr[tid] = v * anew;
    }
    __syncthreads();
    if (tid < 16){
      float s = 0.f;
#pragma unroll
      for (int r = 0; r < 8; ++r) s += pr[tid * 8 + r];
      PART[(pc & 1) * (NBLK * 128) + bid * 128 + tid * 6 + 0] = s;
    }
    __threadfence();
    grid.sync();
    {
      const float* Pb = PART + (pc & 1) * (NBLK * 128);
      float s = 0.f;
      const int sidx = tid & 127, g2 = tid >> 7;
      for (int b = g2; b < NBLK; b += 4) s += Pb[b * 128 + sidx];
      pr[tid] = s;
      __syncthreads();
      if (tid < 96) dsum[tid] = pr[tid] + pr[128 + tid] + pr[256 + tid] + pr[384 + tid];
      __syncthreads();
    }
    if (tid < 16) ca_s[tid] = dsum[tid * 6 + 0];
    __syncthreads();
    ++pc;
    float* tmp = Ac; Ac = An; An = tmp;
  }

  // ---------------- Rollout: 64 sequential steps ----------------------------
  if (tid < 16) xcur[tid] = st0[tid];
  __syncthreads();

#pragma unroll 1
  for (int t = 0; t < HORIZON; ++t){
    if (tid >= 16 && tid < 24) xcur[tid] = act[t * DACT + (tid - 16)];
    __syncthreads();
    // d2 to all training points
    {
      float xl[DIN];
#pragma unroll
      for (int k = 0; k < DIN; ++k) xl[k] = xcur[k];
      for (int p = tid; p < N_TRAIN; p += NTHR){
        const float* xp = xtr + p * DIN;
        float sacc = 0.f;
#pragma unroll
        for (int k = 0; k < DIN; ++k){ float dd = xl[k] - xp[k]; sacc = fmaf(dd, dd, sacc); }
        d2f[p] = sacc;
      }
    }
    __syncthreads();
    // kxs (bf16) into LDS for the sweep
    {
      const int d = tid >> 5, jg = tid & 31;
      const float ced = ce_s[d], vd = var_s[d];
      for (int q = 0; q < CPT; ++q){
        const int j = jg + (q << 5);
        kl[d * KLS + j] = f2bf(vd * fexp2(ced * d2f[j]));
      }
    }
    __syncthreads();
    // own-row exact dots: mean-part, kk-part, c-part  -> PART slots 0..2
    if (tid < 128){
      const int dd = tid >> 3, r = tid & 7;
      const int rowg = rowbase + r;
      float kv = var_s[dd] * fexp2(ce_s[dd] * d2f[rowg]);   // fp32 kxs
      float v  = sig_s[dd] * PVc[dd * N_TRAIN + rowg];
      pr[0 * 128 + tid] = kv * ALPH[dd * N_TRAIN + rowg];
      pr[1 * 128 + tid] = kv * kv;
      pr[2 * 128 + tid] = kv * v;
    }
    __syncthreads();
    if (tid < 48){
      const int slot = tid >> 4, dd = tid & 15;
      float s = 0.f;
#pragma unroll
      for (int r = 0; r < 8; ++r) s += pr[slot * 128 + dd * 8 + r];
      PART[(pc & 1) * (NBLK * 128) + bid * 128 + dd * 6 + slot] = s;
    }
    // w = G * kxs over this block's rows
    sweep_block<1>(sq, (const float*)0, kl, ce_s, g_s, wfin, rowbase, tid);
    if (tid < 128){
      const int dd = tid >> 3, r = tid & 7;
      const int rowg = rowbase + r;
      float w  = wfin[r * 16 + dd];
      float kv = var_s[dd] * fexp2(ce_s[dd] * d2f[rowg]);
      float v  = sig_s[dd] * PVc[dd * N_TRAIN + rowg];
      pr[0 * 128 + tid] = kv * w;
      pr[1 * 128 + tid] = w * w;
      pr[2 * 128 + tid] = v * w;
    }
    __syncthreads();
    if (tid < 48){
      const int slot = tid >> 4, dd = tid & 15;
      float s = 0.f;
#pragma unroll
      for (int r = 0; r < 8; ++r) s += pr[slot * 128 + dd * 8 + r];
      PART[(pc & 1) * (NBLK * 128) + bid * 128 + dd * 6 + 3 + slot] = s;
    }
    __threadfence();
    grid.sync();
    // reduce partials (every block, redundantly)
    {
      const float* Pb = PART + (pc & 1) * (NBLK * 128);
      float s = 0.f;
      const int sidx = tid & 127, g2 = tid >> 7;
      for (int b = g2; b < NBLK; b += 4) s += Pb[b * 128 + sidx];
      pr[tid] = s;
      __syncthreads();
      if (tid < 96) dsum[tid] = pr[tid] + pr[128 + tid] + pr[256 + tid] + pr[384 + tid];
      __syncthreads();
    }
    if (tid < 16){
      const int dd = tid;
      float mean = dsum[dd * 6 + 0], kk = dsum[dd * 6 + 1], c  = dsum[dd * 6 + 2];
      float kw   = dsum[dd * 6 + 3], ww = dsum[dd * 6 + 4], vw = dsum[dd * 6 + 5];
      float lam = lam_s[dd];
      // q*s = c^2/(1+lam) + p'p - p'Gp + |Gp - lam*c*v|^2   (2nd-order Neumann on deflated G)
      float qs = c * c / (1.f + lam) + (kk - c * c) - (kw - c * vw)
               + (ww - 2.f * lam * c * vw + lam * lam * c * c);
      float q  = qs / s_s[dd];
      float pvv = var_s[dd] - q + nv_s[dd];
      float sd = sqrtf(fmaxf(pvv, 1e-12f));
      float ns = mean + sd * eps[t * DOUT + dd];
      xcur[dd] = ns;
      float rs = ns, cs = ns * ns;
      rs += __shfl_down(rs, 8);  cs += __shfl_down(cs, 8);
      rs += __shfl_down(rs, 4);  cs += __shfl_down(cs, 4);
      rs += __shfl_down(rs, 2);  cs += __shfl_down(cs, 2);
      rs += __shfl_down(rs, 1);  cs += __shfl_down(cs, 1);
      if (bid == 0){
        out[t * DOUT + dd]        = ns;     // trajectory
        out[1152 + t * DOUT + dd] = mean;   // means
        out[2176 + t * DOUT + dd] = sd;     // stds
        if (dd == 0){ out[1024 + t] = rs; out[1088 + t] = cs; }  // reward, cost
      }
    }
    __syncthreads();
    ++pc;
  }
}

extern "C" void kernel_launch(void* const* d_in, const int* in_sizes, int n_in,
                              void* d_out, int out_size, void* d_ws, size_t ws_size,
                              hipStream_t stream) {
  (void)in_sizes; (void)n_in; (void)out_size; (void)ws_size;
  const float* xtr = (const float*)d_in[0];
  const float* ytr = (const float*)d_in[1];
  const float* ls  = (const float*)d_in[2];
  const float* var = (const float*)d_in[3];
  const float* noi = (const float*)d_in[4];
  const float* st0 = (const float*)d_in[5];
  const float* act = (const float*)d_in[6];
  const float* eps = (const float*)d_in[7];
  float* out = (float*)d_out;
  float* ws  = (float*)d_ws;
  void* args[] = { &xtr, &ytr, &ls, &var, &noi, &st0, &act, &eps, &out, &ws };
  hipLaunchCooperativeKernel((const void*)gp_rollout_kernel,
                             dim3(NBLK), dim3(NTHR), args, 0, stream);
}

// Round 2
// 3836.439 us; speedup vs baseline: 2.3378x; 2.3378x over previous
//
#include <hip/hip_runtime.h>
#include <hip/hip_fp16.h>
#include <hip/hip_cooperative_groups.h>

namespace cg = cooperative_groups;

#define N_TRAIN   2048
#define DOUT      16
#define DACT      8
#define DIN       24
#define HORIZON   64
#define JITTER    1e-6f

#define NBLK      256
#define NTHR      1024
#define RPB       8        // rows per block: 2048/256
#define SQS       2056     // fp16 sq LDS stride
#define KLS       2052     // bf16 kl LDS stride

#define POWER_ITERS 6
#define RICH_ITERS  10

// workspace layout (float indices)
#define OFF_PV0   0
#define OFF_PV1   32768
#define OFF_AA0   65536
#define OFF_AA1   98304
#define OFF_AL    131072
#define OFF_XT    163840               // xtrT [24][2048] fp32
#define OFF_RES   212992               // 128 phases * 96 slots * 8 lanes
#define OFF_CTR   311296

__device__ __forceinline__ float fexp2(float x){ return __builtin_amdgcn_exp2f(x); }

__device__ __forceinline__ float bf2f(unsigned short u){
  union { unsigned int i; float f; } v; v.i = ((unsigned int)u) << 16; return v.f;
}
__device__ __forceinline__ unsigned short f2bf(float f){
  union { float f; unsigned int i; } v; v.f = f;
  unsigned int r = v.i + 0x7fffu + ((v.i >> 16) & 1u);
  return (unsigned short)(r >> 16);
}

// custom grid barrier: monotonic counter, one slot per phase never reused.
// Mirrors cg::grid.sync() protocol (release fence / arrive / spin / acquire
// fence) but with s_sleep backoff and nothing else on the critical path.
__device__ __forceinline__ void gbar(unsigned int* ctr, int pc){
  __syncthreads();                       // drains each wave's vmcnt -> stores in L2
  if (threadIdx.x == 0){
    __threadfence();                     // release: L2 writeback to coherence point
    atomicAdd(ctr, 1u);
    while (__hip_atomic_load(ctr, __ATOMIC_RELAXED, __HIP_MEMORY_SCOPE_AGENT)
           < (unsigned int)(pc * NBLK)){
      __builtin_amdgcn_s_sleep(1);
    }
    __threadfence();                     // acquire: invalidate stale L1/L2
  }
  __syncthreads();
}

// w = G_d * u over this block's 8 rows, sq from LDS fp16.
// MODE 0: u from global V [d][2048] fp32.  MODE 1: u from LDS kl bf16.
template<int MODE>
__device__ __forceinline__ void sweep(const __half* sqh, const float* __restrict__ V,
                                      const unsigned short* kl, float ce, float gd,
                                      float* wfin, int rowbase, int d, int jg)
{
  float acc[RPB];
#pragma unroll
  for (int r = 0; r < RPB; ++r) acc[r] = 0.f;
#pragma unroll
  for (int half = 0; half < 2; ++half){
    float2 uu[8];
#pragma unroll
    for (int t = 0; t < 8; ++t){
      const int j = 2*jg + 128*(half*8 + t);
      if (MODE == 0){
        uu[t] = *reinterpret_cast<const float2*>(&V[d * N_TRAIN + j]);
      } else {
        unsigned int pk = *reinterpret_cast<const unsigned int*>(&kl[d * KLS + j]);
        uu[t] = make_float2(bf2f((unsigned short)(pk & 0xffffu)),
                            bf2f((unsigned short)(pk >> 16)));
      }
    }
#pragma unroll
    for (int t = 0; t < 8; ++t){
      const int j = 2*jg + 128*(half*8 + t);
#pragma unroll
      for (int r = 0; r < RPB; ++r){
        __half2 h2 = *reinterpret_cast<const __half2*>(&sqh[r * SQS + j]);
        float2 f2 = __half22float2(h2);
        acc[r] = fmaf(fexp2(ce * f2.x), uu[t].x, acc[r]);
        acc[r] = fmaf(fexp2(ce * f2.y), uu[t].y, acc[r]);
      }
    }
  }
#pragma unroll
  for (int r = 0; r < RPB; ++r){
    acc[r] += __shfl_xor(acc[r], 1);
    acc[r] += __shfl_xor(acc[r], 2);
    acc[r] += __shfl_xor(acc[r], 4);
    acc[r] += __shfl_xor(acc[r], 8);
    acc[r] += __shfl_xor(acc[r], 16);
    acc[r] += __shfl_xor(acc[r], 32);
  }
  if (jg == 0){
#pragma unroll
    for (int r = 0; r < RPB; ++r){
      const int rowg = rowbase + r;
      float ud;
      if (MODE == 0) ud = V[d * N_TRAIN + rowg];
      else           ud = bf2f(kl[d * KLS + rowg]);
      wfin[r * 16 + d] = gd * (acc[r] - ud);   // subtract diagonal (sq=0 -> exp=1)
    }
  }
}

__global__ __launch_bounds__(NTHR, 1)
void gp_rollout_kernel(const float* __restrict__ xtr, const float* __restrict__ ytr,
                       const float* __restrict__ ls,  const float* __restrict__ var,
                       const float* __restrict__ noi, const float* __restrict__ st0,
                       const float* __restrict__ act, const float* __restrict__ eps,
                       float* __restrict__ out, float* __restrict__ ws)
{
  cg::grid_group grid = cg::this_grid();
  const int tid = threadIdx.x;
  const int bid = blockIdx.x;
  const int rowbase = bid * RPB;

  float* PV0  = ws + OFF_PV0;
  float* PV1  = ws + OFF_PV1;
  float* AA0  = ws + OFF_AA0;
  float* AA1  = ws + OFF_AA1;
  float* ALPH = ws + OFF_AL;
  float* XT   = ws + OFF_XT;
  float* RES  = ws + OFF_RES;
  unsigned int* ctr = (unsigned int*)(ws + OFF_CTR);

  __shared__ __half sqh[RPB * SQS];            // 32.9 KB, this block's sq rows
  __shared__ unsigned short kl[DOUT * KLS];    // 65.7 KB, bf16 kxs
  __shared__ float d2f[N_TRAIN];               // 8 KB
  __shared__ float pr[384];
  __shared__ float wfin[128];
  __shared__ float dsum[96];
  __shared__ float xcur[DIN];
  __shared__ float xrows[RPB * DIN];
  __shared__ float ce_s[16], g_s[16], s_s[16], var_s[16], nv_s[16];
  __shared__ float un_s[16], lam_s[16], sig_s[16], cb_s[16], ca_s[16];

  if (tid < 16){
    float l2 = ls[tid] * ls[tid];
    float nv = noi[tid] * noi[tid];
    float sd = var[tid] + nv + JITTER;
    ce_s[tid]  = -0.72134752044448f / l2;   // -0.5*log2(e)/ls^2
    g_s[tid]   = var[tid] / sd;
    s_s[tid]   = sd;
    var_s[tid] = var[tid];
    nv_s[tid]  = nv;
    un_s[tid]  = (float)N_TRAIN;            // ||ones||^2
  }

  // -------- Phase 0: sq rows -> LDS fp16; xtrT; PV0=1; zero RES/ctr --------
  if (tid < RPB * DIN) xrows[tid] = xtr[rowbase * DIN + tid];
  __syncthreads();
  {
    const int r  = tid >> 7;      // 0..7, 128 threads per row
    const int c0 = tid & 127;
    float xl[DIN];
#pragma unroll
    for (int k = 0; k < DIN; ++k) xl[k] = xrows[r * DIN + k];
    for (int q = 0; q < 16; ++q){
      const int j = c0 + (q << 7);
      const float4* xp = reinterpret_cast<const float4*>(xtr + j * DIN);
      float sacc = 0.f;
#pragma unroll
      for (int v4 = 0; v4 < 6; ++v4){
        float4 x4 = xp[v4];
        float e0 = xl[v4*4+0] - x4.x, e1 = xl[v4*4+1] - x4.y;
        float e2 = xl[v4*4+2] - x4.z, e3 = xl[v4*4+3] - x4.w;
        sacc = fmaf(e0,e0, fmaf(e1,e1, fmaf(e2,e2, fmaf(e3,e3, sacc))));
      }
      sqh[r * SQS + j] = __float2half_rn(sacc);
    }
  }
  if (tid < RPB * DIN){
    int r = tid / DIN, k = tid % DIN;
    XT[k * N_TRAIN + rowbase + r] = xrows[r * DIN + k];
  }
  if (tid < 128){
    int dd = tid >> 3, r = tid & 7;
    PV0[dd * N_TRAIN + rowbase + r] = 1.0f;
  }
  if (tid < 384) RES[bid * 384 + tid] = 0.f;   // 256*384 = 128 phases * 768
  if (bid == 0 && tid == 0) *ctr = 0u;
  __syncthreads();
  __threadfence();
  grid.sync();            // the single cooperative sync (init visibility)
  int pc = 0;

  const int d  = tid >> 6;   // 0..15, one wave per output
  const int jg = tid & 63;
  const int lane8 = bid & 7; // atomic contention lane

  // -------- Power iteration --------------------------------------------------
  float* PVc = PV0; float* PVn = PV1;
#pragma unroll 1
  for (int it = 0; it < POWER_ITERS; ++it){
    const bool last = (it == POWER_ITERS - 1);
    sweep<0>(sqh, PVc, kl, ce_s[d], g_s[d], wfin, rowbase, d, jg);
    __syncthreads();
    if (tid < 128){
      const int dd = tid >> 3, r = tid & 7, rowg = rowbase + r;
      float w = wfin[r * 16 + dd];
      PVn[dd * N_TRAIN + rowg] = w;
      float u = PVc[dd * N_TRAIN + rowg];
      pr[tid]       = w * w;
      pr[128 + tid] = u * w;
      pr[256 + tid] = last ? (ytr[rowg * 16 + dd] / s_s[dd]) * w : 0.f;
    }
    __syncthreads();
    ++pc;
    if (tid < 48){
      const int slot = tid >> 4, dd = tid & 15;
      float s = 0.f;
#pragma unroll
      for (int r = 0; r < 8; ++r) s += pr[slot * 128 + dd * 8 + r];
      atomicAdd(&RES[pc * 768 + (dd * 6 + slot) * 8 + lane8], s);
    }
    gbar(ctr, pc);
    if (tid < 96){
      const float4* rp = reinterpret_cast<const float4*>(&RES[pc * 768 + tid * 8]);
      float4 a = rp[0], b = rp[1];
      dsum[tid] = a.x + a.y + a.z + a.w + b.x + b.y + b.z + b.w;
    }
    __syncthreads();
    if (tid < 16){
      float ww = dsum[tid * 6 + 0];
      float uw = dsum[tid * 6 + 1];
      if (last){
        lam_s[tid] = uw / fmaxf(un_s[tid], 1e-30f);   // Rayleigh quotient
        float sg = rsqrtf(fmaxf(ww, 1e-38f));
        sig_s[tid] = sg;
        cb_s[tid]  = sg * dsum[tid * 6 + 2];           // v1^T (y/s)
      }
      un_s[tid] = ww;
    }
    __syncthreads();
    float* tmp = PVc; PVc = PVn; PVn = tmp;
  }

  // -------- a0 = b - cb*v1 ; analytically v^T a0 = 0 -------------------------
  if (tid < 128){
    const int dd = tid >> 3, r = tid & 7, rowg = rowbase + r;
    float v = sig_s[dd] * PVc[dd * N_TRAIN + rowg];
    float b = ytr[rowg * 16 + dd] / s_s[dd];
    AA0[dd * N_TRAIN + rowg] = b - cb_s[dd] * v;
  }
  if (tid < 16) ca_s[tid] = 0.f;                 // v unit => v^T a0 = cb - cb = 0
  ++pc;
  gbar(ctr, pc);                                  // visibility of AA0 only

  // -------- Richardson on deflated operator ----------------------------------
  float* Ac = AA0; float* An = AA1;
#pragma unroll 1
  for (int it = 0; it < RICH_ITERS; ++it){
    const bool last = (it == RICH_ITERS - 1);
    sweep<0>(sqh, Ac, kl, ce_s[d], g_s[d], wfin, rowbase, d, jg);
    __syncthreads();
    if (tid < 128){
      const int dd = tid >> 3, r = tid & 7, rowg = rowbase + r;
      float w = wfin[r * 16 + dd];
      float v = sig_s[dd] * PVc[dd * N_TRAIN + rowg];
      float b = ytr[rowg * 16 + dd] / s_s[dd];
      float bperp = b - cb_s[dd] * v;
      float anew = bperp - (w - lam_s[dd] * ca_s[dd] * v);
      float aout = last ? (anew + (cb_s[dd] / (1.f + lam_s[dd])) * v) : anew;
      float* dst = last ? ALPH : An;
      dst[dd * N_TRAIN + rowg] = aout;
      pr[tid] = v * anew;
    }
    __syncthreads();
    ++pc;
    if (tid < 16){
      float s = 0.f;
#pragma unroll
      for (int r = 0; r < 8; ++r) s += pr[tid * 8 + r];
      atomicAdd(&RES[pc * 768 + tid * 6 * 8 + lane8], s);
    }
    gbar(ctr, pc);
    if (tid < 16){
      const float4* rp = reinterpret_cast<const float4*>(&RES[pc * 768 + tid * 48]);
      float4 a = rp[0], b = rp[1];
      ca_s[tid] = a.x + a.y + a.z + a.w + b.x + b.y + b.z + b.w;
    }
    __syncthreads();
    float* tmp = Ac; Ac = An; An = tmp;
  }

  // -------- Rollout ----------------------------------------------------------
  if (tid < 16) xcur[tid] = st0[tid];
  __syncthreads();

#pragma unroll 1
  for (int t = 0; t < HORIZON; ++t){
    if (tid >= 16 && tid < 24) xcur[tid] = act[t * DACT + (tid - 16)];
    __syncthreads();
    // d2 via transposed xtr (fully coalesced)
    {
      float xl[DIN];
#pragma unroll
      for (int k = 0; k < DIN; ++k) xl[k] = xcur[k];
#pragma unroll
      for (int h = 0; h < 2; ++h){
        const int p = tid + h * NTHR;
        float sacc = 0.f;
#pragma unroll
        for (int k = 0; k < DIN; ++k){
          float e = xl[k] - XT[k * N_TRAIN + p];
          sacc = fmaf(e, e, sacc);
        }
        d2f[p] = sacc;
      }
    }
    __syncthreads();
    // kxs bf16 -> LDS
    {
      const float ced = ce_s[d], vd = var_s[d];
      for (int q = 0; q < 16; ++q){
        const int j = 2*jg + (q << 7);
        float k0 = vd * fexp2(ced * d2f[j]);
        float k1 = vd * fexp2(ced * d2f[j + 1]);
        unsigned int pk = (unsigned int)f2bf(k0) | ((unsigned int)f2bf(k1) << 16);
        *reinterpret_cast<unsigned int*>(&kl[d * KLS + j]) = pk;
      }
    }
    __syncthreads();
    ++pc;
    // own-row exact dots (slots 0..2)
    if (tid < 128){
      const int dd = tid >> 3, r = tid & 7, rowg = rowbase + r;
      float kv = var_s[dd] * fexp2(ce_s[dd] * d2f[rowg]);
      float v  = sig_s[dd] * PVc[dd * N_TRAIN + rowg];
      pr[tid]       = kv * ALPH[dd * N_TRAIN + rowg];
      pr[128 + tid] = kv * kv;
      pr[256 + tid] = kv * v;
    }
    __syncthreads();
    if (tid < 48){
      const int slot = tid >> 4, dd = tid & 15;
      float s = 0.f;
#pragma unroll
      for (int r = 0; r < 8; ++r) s += pr[slot * 128 + dd * 8 + r];
      atomicAdd(&RES[pc * 768 + (dd * 6 + slot) * 8 + lane8], s);
    }
    // w = G * kxs (slots 3..5)
    sweep<1>(sqh, (const float*)0, kl, ce_s[d], g_s[d], wfin, rowbase, d, jg);
    __syncthreads();
    if (tid < 128){
      const int dd = tid >> 3, r = tid & 7, rowg = rowbase + r;
      float w  = wfin[r * 16 + dd];
      float kv = var_s[dd] * fexp2(ce_s[dd] * d2f[rowg]);
      float v  = sig_s[dd] * PVc[dd * N_TRAIN + rowg];
      pr[tid]       = kv * w;
      pr[128 + tid] = w * w;
      pr[256 + tid] = v * w;
    }
    __syncthreads();
    if (tid < 48){
      const int slot = tid >> 4, dd = tid & 15;
      float s = 0.f;
#pragma unroll
      for (int r = 0; r < 8; ++r) s += pr[slot * 128 + dd * 8 + r];
      atomicAdd(&RES[pc * 768 + (dd * 6 + 3 + slot) * 8 + lane8], s);
    }
    gbar(ctr, pc);
    if (tid < 96){
      const float4* rp = reinterpret_cast<const float4*>(&RES[pc * 768 + tid * 8]);
      float4 a = rp[0], b = rp[1];
      dsum[tid] = a.x + a.y + a.z + a.w + b.x + b.y + b.z + b.w;
    }
    __syncthreads();
    if (tid < 16){
      const int dd = tid;
      float mean = dsum[dd*6+0], kk = dsum[dd*6+1], c  = dsum[dd*6+2];
      float kw   = dsum[dd*6+3], ww = dsum[dd*6+4], vw = dsum[dd*6+5];
      float lam = lam_s[dd];
      float qs = c * c / (1.f + lam) + (kk - c * c) - (kw - c * vw)
               + (ww - 2.f * lam * c * vw + lam * lam * c * c);
      float q  = qs / s_s[dd];
      float pvv = var_s[dd] - q + nv_s[dd];
      float sd = sqrtf(fmaxf(pvv, 1e-12f));
      float ns = mean + sd * eps[t * DOUT + dd];
      xcur[dd] = ns;
      float rs = ns, cs = ns * ns;
      rs += __shfl_down(rs, 8);  cs += __shfl_down(cs, 8);
      rs += __shfl_down(rs, 4);  cs += __shfl_down(cs, 4);
      rs += __shfl_down(rs, 2);  cs += __shfl_down(cs, 2);
      rs += __shfl_down(rs, 1);  cs += __shfl_down(cs, 1);
      if (bid == 0){
        out[t * DOUT + dd]        = ns;
        out[1152 + t * DOUT + dd] = mean;
        out[2176 + t * DOUT + dd] = sd;
        if (dd == 0){ out[1024 + t] = rs; out[1088 + t] = cs; }
      }
    }
    __syncthreads();
  }
}

extern "C" void kernel_launch(void* const* d_in, const int* in_sizes, int n_in,
                              void* d_out, int out_size, void* d_ws, size_t ws_size,
                              hipStream_t stream) {
  (void)in_sizes; (void)n_in; (void)out_size; (void)ws_size;
  const float* xtr = (const float*)d_in[0];
  const float* ytr = (const float*)d_in[1];
  const float* ls  = (const float*)d_in[2];
  const float* var = (const float*)d_in[3];
  const float* noi = (const float*)d_in[4];
  const float* st0 = (const float*)d_in[5];
  const float* act = (const float*)d_in[6];
  const float* eps = (const float*)d_in[7];
  float* out = (float*)d_out;
  float* ws  = (float*)d_ws;
  void* args[] = { &xtr, &ytr, &ls, &var, &noi, &st0, &act, &eps, &out, &ws };
  hipLaunchCooperativeKernel((const void*)gp_rollout_kernel,
                             dim3(NBLK), dim3(NTHR), args, 0, stream);
}

// Round 3
// 1920.033 us; speedup vs baseline: 4.6712x; 1.9981x over previous
//
#include <hip/hip_runtime.h>
#include <hip/hip_fp16.h>
#include <hip/hip_cooperative_groups.h>

namespace cg = cooperative_groups;

#define N_TRAIN   2048
#define DOUT      16
#define DACT      8
#define DIN       24
#define HORIZON   64
#define JITTER    1e-6f

#define NBLK      256
#define NTHR      1024
#define RPB       8        // rows per block: 2048/256
#define SQS       2056     // fp16 sq LDS stride (16B-aligned rows)
#define KLS       2056     // bf16 kl LDS stride (16B-aligned rows)

#define POWER_ITERS 6
#define RICH_ITERS  10

// workspace layout (float indices)
#define OFF_PV0   0
#define OFF_PV1   32768
#define OFF_AA0   65536
#define OFF_AA1   98304
#define OFF_XT    131072               // xtrT [24][2048] fp32
#define OFF_RES   180224               // 128 phases * 96 slots * 8 lanes
#define OFF_SYNC  278528               // u32: [0]=ctr, [32+i*16]=gen flag i

__device__ __forceinline__ float fexp2(float x){ return __builtin_amdgcn_exp2f(x); }

__device__ __forceinline__ float bf2f(unsigned short u){
  union { unsigned int i; float f; } v; v.i = ((unsigned int)u) << 16; return v.f;
}
__device__ __forceinline__ unsigned short f2bf(float f){
  union { float f; unsigned int i; } v; v.f = f;
  unsigned int r = v.i + 0x7fffu + ((v.i >> 16) & 1u);
  return (unsigned short)(r >> 16);
}

// L2-bypassing 8-byte load (reads the coherence point directly)
__device__ __forceinline__ float2 aload2(const float* p){
  unsigned long long v = __hip_atomic_load((unsigned long long*)p,
                                           __ATOMIC_RELAXED, __HIP_MEMORY_SCOPE_AGENT);
  union { unsigned long long u; float2 f; } c; c.u = v; return c.f;
}

// Two-level grid barrier. Arrivals hit one counter; ONLY block 0 spins on it,
// then publishes pc to 8 generation flags (separate cache lines); followers
// spin on their own flag. FENCE=true adds the release/acquire pair needed when
// regular (cached) stores cross the barrier; FENCE=false relies on all
// cross-block data being device-scope atomics (no L2 invalidate -> L2 stays hot).
template<bool FENCE>
__device__ __forceinline__ void gbar(unsigned int* sync, int pc, int bid){
  __syncthreads();
  if (threadIdx.x == 0){
    __threadfence();                       // release (wbl2; near-no dirty lines in rollout)
    atomicAdd(&sync[0], 1u);
    if (bid == 0){
      while (__hip_atomic_load(&sync[0], __ATOMIC_RELAXED, __HIP_MEMORY_SCOPE_AGENT)
             < (unsigned int)pc * NBLK){
        __builtin_amdgcn_s_sleep(2);
      }
#pragma unroll
      for (int i = 0; i < 8; ++i)
        __hip_atomic_store(&sync[32 + i * 16], (unsigned int)pc,
                           __ATOMIC_RELAXED, __HIP_MEMORY_SCOPE_AGENT);
    } else {
      unsigned int* g = &sync[32 + (bid & 7) * 16];
      while (__hip_atomic_load(g, __ATOMIC_RELAXED, __HIP_MEMORY_SCOPE_AGENT)
             < (unsigned int)pc){
        __builtin_amdgcn_s_sleep(4);
      }
    }
    if (FENCE) __threadfence();            // acquire: invalidate L1/L2
  }
  __syncthreads();
}

// w = G_d * u over this block's 8 rows; sq from LDS fp16 (16B vector reads).
// MODE 0: u from global V [d][2048] fp32.  MODE 1: u from LDS kl bf16.
template<int MODE>
__device__ __forceinline__ void sweep(const __half* sqh, const float* __restrict__ V,
                                      const unsigned short* kl, float ce, float gd,
                                      float* wfin, int rowbase, int d, int jg)
{
  float acc[RPB];
#pragma unroll
  for (int r = 0; r < RPB; ++r) acc[r] = 0.f;
#pragma unroll
  for (int seg = 0; seg < 4; ++seg){
    const int j0 = 8 * jg + 512 * seg;
    float u[8];
    if (MODE == 0){
      float4 ua = *reinterpret_cast<const float4*>(&V[d * N_TRAIN + j0]);
      float4 ub = *reinterpret_cast<const float4*>(&V[d * N_TRAIN + j0 + 4]);
      u[0]=ua.x; u[1]=ua.y; u[2]=ua.z; u[3]=ua.w;
      u[4]=ub.x; u[5]=ub.y; u[6]=ub.z; u[7]=ub.w;
    } else {
      uint4 pk = *reinterpret_cast<const uint4*>(&kl[d * KLS + j0]);
      u[0]=bf2f((unsigned short)(pk.x&0xffffu)); u[1]=bf2f((unsigned short)(pk.x>>16));
      u[2]=bf2f((unsigned short)(pk.y&0xffffu)); u[3]=bf2f((unsigned short)(pk.y>>16));
      u[4]=bf2f((unsigned short)(pk.z&0xffffu)); u[5]=bf2f((unsigned short)(pk.z>>16));
      u[6]=bf2f((unsigned short)(pk.w&0xffffu)); u[7]=bf2f((unsigned short)(pk.w>>16));
    }
#pragma unroll
    for (int r = 0; r < RPB; ++r){
      uint4 sp = *reinterpret_cast<const uint4*>(&sqh[r * SQS + j0]);
      unsigned int w4[4] = {sp.x, sp.y, sp.z, sp.w};
#pragma unroll
      for (int e = 0; e < 4; ++e){
        __half2 h2 = *reinterpret_cast<const __half2*>(&w4[e]);
        float2 f2 = __half22float2(h2);
        acc[r] = fmaf(fexp2(ce * f2.x), u[2*e],   acc[r]);
        acc[r] = fmaf(fexp2(ce * f2.y), u[2*e+1], acc[r]);
      }
    }
  }
#pragma unroll
  for (int r = 0; r < RPB; ++r){
    acc[r] += __shfl_xor(acc[r], 1);
    acc[r] += __shfl_xor(acc[r], 2);
    acc[r] += __shfl_xor(acc[r], 4);
    acc[r] += __shfl_xor(acc[r], 8);
    acc[r] += __shfl_xor(acc[r], 16);
    acc[r] += __shfl_xor(acc[r], 32);
  }
  if (jg == 0){
#pragma unroll
    for (int r = 0; r < RPB; ++r){
      const int rowg = rowbase + r;
      float ud;
      if (MODE == 0) ud = V[d * N_TRAIN + rowg];
      else           ud = bf2f(kl[d * KLS + rowg]);
      wfin[r * 16 + d] = gd * (acc[r] - ud);   // subtract diagonal (sq=0 -> exp=1)
    }
  }
}

__global__ __launch_bounds__(NTHR, 1)
void gp_rollout_kernel(const float* __restrict__ xtr, const float* __restrict__ ytr,
                       const float* __restrict__ ls,  const float* __restrict__ var,
                       const float* __restrict__ noi, const float* __restrict__ st0,
                       const float* __restrict__ act, const float* __restrict__ eps,
                       float* __restrict__ out, float* __restrict__ ws)
{
  cg::grid_group grid = cg::this_grid();
  const int tid = threadIdx.x;
  const int bid = blockIdx.x;
  const int rowbase = bid * RPB;

  float* PV0  = ws + OFF_PV0;
  float* PV1  = ws + OFF_PV1;
  float* AA0  = ws + OFF_AA0;
  float* AA1  = ws + OFF_AA1;
  float* XT   = ws + OFF_XT;
  float* RES  = ws + OFF_RES;
  unsigned int* syn = (unsigned int*)(ws + OFF_SYNC);

  __shared__ __half sqh[RPB * SQS];            // 32.9 KB
  __shared__ unsigned short kl[DOUT * KLS];    // 65.8 KB
  __shared__ float d2f[N_TRAIN];               // 8 KB
  __shared__ float act_s[HORIZON * DACT];      // 2 KB
  __shared__ float eps_s[HORIZON * DOUT];      // 4 KB
  __shared__ float pr[384];
  __shared__ float wfin[128];
  __shared__ float dsum[96];
  __shared__ float xcur[32];
  __shared__ float xrows[RPB * DIN];
  __shared__ float pv_s[128], v_s[128], al_s[128], yb_s[128];
  __shared__ float ce_s[16], g_s[16], s_s[16], var_s[16], nv_s[16];
  __shared__ float un_s[16], lam_s[16], sig_s[16], cb_s[16], ca_s[16];

  if (tid < 16){
    float l2 = ls[tid] * ls[tid];
    float nv = noi[tid] * noi[tid];
    float sd = var[tid] + nv + JITTER;
    ce_s[tid]  = -0.72134752044448f / l2;   // -0.5*log2(e)/ls^2
    g_s[tid]   = var[tid] / sd;
    s_s[tid]   = sd;
    var_s[tid] = var[tid];
    nv_s[tid]  = nv;
    un_s[tid]  = (float)N_TRAIN;            // ||ones||^2
  }
  if (tid < RPB * DIN) xrows[tid] = xtr[rowbase * DIN + tid];
  if (tid < HORIZON * DACT) act_s[tid] = act[tid];
  if (tid < HORIZON * DOUT) eps_s[tid] = eps[tid];
  __syncthreads();

  // -------- Phase 0: sq rows -> LDS fp16; xtrT; own-row caches; zero sync ---
  if (tid < 128){
    const int dd = tid >> 3, r = tid & 7;
    yb_s[tid] = ytr[(rowbase + r) * DOUT + dd] / s_s[dd];
    PV0[dd * N_TRAIN + rowbase + r] = 1.0f;
    pv_s[tid] = 1.0f;
  }
  {
    const int r  = tid >> 7;      // 0..7, 128 threads per row
    const int c0 = tid & 127;
    float xl[DIN];
#pragma unroll
    for (int k = 0; k < DIN; ++k) xl[k] = xrows[r * DIN + k];
    for (int q = 0; q < 16; ++q){
      const int j = c0 + (q << 7);
      const float4* xp = reinterpret_cast<const float4*>(xtr + j * DIN);
      float sacc = 0.f;
#pragma unroll
      for (int v4 = 0; v4 < 6; ++v4){
        float4 x4 = xp[v4];
        float e0 = xl[v4*4+0] - x4.x, e1 = xl[v4*4+1] - x4.y;
        float e2 = xl[v4*4+2] - x4.z, e3 = xl[v4*4+3] - x4.w;
        sacc = fmaf(e0,e0, fmaf(e1,e1, fmaf(e2,e2, fmaf(e3,e3, sacc))));
      }
      sqh[r * SQS + j] = __float2half_rn(sacc);
    }
  }
  if (tid < RPB * DIN){
    int r = tid / DIN, k = tid % DIN;
    XT[k * N_TRAIN + rowbase + r] = xrows[r * DIN + k];
  }
  if (tid < 384) RES[bid * 384 + tid] = 0.f;   // 256*384 = 128 phases * 768
  if (bid == 0 && tid < 160) syn[tid] = 0u;    // ctr + gen flags
  __syncthreads();
  __threadfence();
  grid.sync();            // single cooperative sync: init visibility everywhere
  int pc = 0;

  const int d  = tid >> 6;   // 0..15, one wave per output
  const int jg = tid & 63;
  const int lane8 = bid & 7; // atomic contention lane

  // -------- Power iteration --------------------------------------------------
  float* PVc = PV0; float* PVn = PV1;
#pragma unroll 1
  for (int it = 0; it < POWER_ITERS; ++it){
    const bool last = (it == POWER_ITERS - 1);
    sweep<0>(sqh, PVc, kl, ce_s[d], g_s[d], wfin, rowbase, d, jg);
    __syncthreads();
    if (tid < 128){
      const int dd = tid >> 3, r = tid & 7, rowg = rowbase + r;
      float w = wfin[r * 16 + dd];
      PVn[dd * N_TRAIN + rowg] = w;
      float u = pv_s[tid];
      pv_s[tid] = w;
      pr[tid]       = w * w;
      pr[128 + tid] = u * w;
      pr[256 + tid] = last ? yb_s[tid] * w : 0.f;
    }
    __syncthreads();
    ++pc;
    if (tid < 48){
      const int slot = tid >> 4, dd = tid & 15;
      float s = 0.f;
#pragma unroll
      for (int r = 0; r < 8; ++r) s += pr[slot * 128 + dd * 8 + r];
      atomicAdd(&RES[pc * 768 + (dd * 6 + slot) * 8 + lane8], s);
    }
    gbar<true>(syn, pc, bid);
    if (tid < 96){
      const float4* rp = reinterpret_cast<const float4*>(&RES[pc * 768 + tid * 8]);
      float4 a = rp[0], b = rp[1];
      dsum[tid] = a.x + a.y + a.z + a.w + b.x + b.y + b.z + b.w;
    }
    __syncthreads();
    if (tid < 16){
      float ww = dsum[tid * 6 + 0];
      float uw = dsum[tid * 6 + 1];
      if (last){
        lam_s[tid] = uw / fmaxf(un_s[tid], 1e-30f);   // Rayleigh quotient
        float sg = rsqrtf(fmaxf(ww, 1e-38f));
        sig_s[tid] = sg;
        cb_s[tid]  = sg * dsum[tid * 6 + 2];           // v1^T (y/s)
      }
      un_s[tid] = ww;
    }
    __syncthreads();
    float* tmp = PVc; PVc = PVn; PVn = tmp;
  }

  // -------- a0 = b - cb*v1 ; analytically v^T a0 = 0 -------------------------
  if (tid < 128){
    const int dd = tid >> 3, r = tid & 7, rowg = rowbase + r;
    float v = sig_s[dd] * pv_s[tid];
    v_s[tid] = v;
    AA0[dd * N_TRAIN + rowg] = yb_s[tid] - cb_s[dd] * v;
  }
  if (tid < 16) ca_s[tid] = 0.f;                 // v unit => v^T a0 = cb - cb = 0
  ++pc;
  gbar<true>(syn, pc, bid);                      // visibility of AA0

  // -------- Richardson on deflated operator ----------------------------------
  float* Ac = AA0; float* An = AA1;
#pragma unroll 1
  for (int it = 0; it < RICH_ITERS; ++it){
    const bool last = (it == RICH_ITERS - 1);
    sweep<0>(sqh, Ac, kl, ce_s[d], g_s[d], wfin, rowbase, d, jg);
    __syncthreads();
    if (tid < 128){
      const int dd = tid >> 3, r = tid & 7, rowg = rowbase + r;
      float w = wfin[r * 16 + dd];
      float v = v_s[tid];
      float bperp = yb_s[tid] - cb_s[dd] * v;
      float anew = bperp - (w - lam_s[dd] * ca_s[dd] * v);
      if (last){
        al_s[tid] = anew + (cb_s[dd] / (1.f + lam_s[dd])) * v;   // final alpha (own rows)
      } else {
        An[dd * N_TRAIN + rowg] = anew;
      }
      pr[tid] = v * anew;
    }
    __syncthreads();
    ++pc;
    if (tid < 16){
      float s = 0.f;
#pragma unroll
      for (int r = 0; r < 8; ++r) s += pr[tid * 8 + r];
      atomicAdd(&RES[pc * 768 + tid * 48 + lane8], s);
    }
    gbar<true>(syn, pc, bid);
    if (tid < 16){
      const float4* rp = reinterpret_cast<const float4*>(&RES[pc * 768 + tid * 48]);
      float4 a = rp[0], b = rp[1];
      ca_s[tid] = a.x + a.y + a.z + a.w + b.x + b.y + b.z + b.w;
    }
    __syncthreads();
    float* tmp = Ac; Ac = An; An = tmp;
  }

  // -------- Rollout: fence-free phases, L2 stays hot -------------------------
  if (tid < 16) xcur[tid] = st0[tid];
  __syncthreads();

#pragma unroll 1
  for (int t = 0; t < HORIZON; ++t){
    if (tid >= 16 && tid < 24) xcur[tid] = act_s[t * DACT + (tid - 16)];
    __syncthreads();
    // d2 via transposed xtr (L2-resident; 2 points per thread)
    {
      float xl[DIN];
#pragma unroll
      for (int k = 0; k < DIN; ++k) xl[k] = xcur[k];
      const int p0 = 2 * tid;
      float sx = 0.f, sy = 0.f;
#pragma unroll
      for (int k = 0; k < DIN; ++k){
        float2 xv = *reinterpret_cast<const float2*>(&XT[k * N_TRAIN + p0]);
        float e0 = xl[k] - xv.x, e1 = xl[k] - xv.y;
        sx = fmaf(e0, e0, sx); sy = fmaf(e1, e1, sy);
      }
      *reinterpret_cast<float2*>(&d2f[p0]) = make_float2(sx, sy);
    }
    __syncthreads();
    // kxs bf16 -> LDS (contiguous 16B stores)
    {
      const float ced = ce_s[d], vd = var_s[d];
#pragma unroll
      for (int q = 0; q < 4; ++q){
        const int j0 = 8 * jg + 512 * q;
        float4 a = *reinterpret_cast<const float4*>(&d2f[j0]);
        float4 b = *reinterpret_cast<const float4*>(&d2f[j0 + 4]);
        unsigned int p0 = (unsigned int)f2bf(vd * fexp2(ced * a.x))
                        | ((unsigned int)f2bf(vd * fexp2(ced * a.y)) << 16);
        unsigned int p1 = (unsigned int)f2bf(vd * fexp2(ced * a.z))
                        | ((unsigned int)f2bf(vd * fexp2(ced * a.w)) << 16);
        unsigned int p2 = (unsigned int)f2bf(vd * fexp2(ced * b.x))
                        | ((unsigned int)f2bf(vd * fexp2(ced * b.y)) << 16);
        unsigned int p3 = (unsigned int)f2bf(vd * fexp2(ced * b.z))
                        | ((unsigned int)f2bf(vd * fexp2(ced * b.w)) << 16);
        uint4 pk = make_uint4(p0, p1, p2, p3);
        *reinterpret_cast<uint4*>(&kl[d * KLS + j0]) = pk;
      }
    }
    __syncthreads();
    ++pc;
    // own-row exact dots (slots 0..2) — all from LDS
    if (tid < 128){
      const int dd = tid >> 3, r = tid & 7, rowg = rowbase + r;
      float kv = var_s[dd] * fexp2(ce_s[dd] * d2f[rowg]);
      pr[tid]       = kv * al_s[tid];
      pr[128 + tid] = kv * kv;
      pr[256 + tid] = kv * v_s[tid];
    }
    __syncthreads();
    if (tid < 48){
      const int slot = tid >> 4, dd = tid & 15;
      float s = 0.f;
#pragma unroll
      for (int r = 0; r < 8; ++r) s += pr[slot * 128 + dd * 8 + r];
      atomicAdd(&RES[pc * 768 + (dd * 6 + slot) * 8 + lane8], s);
    }
    // w = G * kxs (slots 3..5)
    sweep<1>(sqh, (const float*)0, kl, ce_s[d], g_s[d], wfin, rowbase, d, jg);
    __syncthreads();
    if (tid < 128){
      const int dd = tid >> 3, r = tid & 7;
      float w  = wfin[r * 16 + dd];
      float kv = var_s[dd] * fexp2(ce_s[dd] * d2f[rowbase + r]);
      pr[tid]       = kv * w;
      pr[128 + tid] = w * w;
      pr[256 + tid] = v_s[tid] * w;
    }
    __syncthreads();
    if (tid < 48){
      const int slot = tid >> 4, dd = tid & 15;
      float s = 0.f;
#pragma unroll
      for (int r = 0; r < 8; ++r) s += pr[slot * 128 + dd * 8 + r];
      atomicAdd(&RES[pc * 768 + (dd * 6 + 3 + slot) * 8 + lane8], s);
    }
    gbar<false>(syn, pc, bid);
    // readback via L2-bypassing atomic loads (no fence, no invalidate)
    if (tid < 96){
      const float* base = &RES[pc * 768 + tid * 8];
      float s = 0.f;
#pragma unroll
      for (int i = 0; i < 4; ++i){ float2 f = aload2(base + 2 * i); s += f.x + f.y; }
      dsum[tid] = s;
    }
    __syncthreads();
    if (tid < 16){
      const int dd = tid;
      float mean = dsum[dd*6+0], kk = dsum[dd*6+1], c  = dsum[dd*6+2];
      float kw   = dsum[dd*6+3], ww = dsum[dd*6+4], vw = dsum[dd*6+5];
      float lam = lam_s[dd];
      float qs = c * c / (1.f + lam) + (kk - c * c) - (kw - c * vw)
               + (ww - 2.f * lam * c * vw + lam * lam * c * c);
      float q  = qs / s_s[dd];
      float pvv = var_s[dd] - q + nv_s[dd];
      float sd = sqrtf(fmaxf(pvv, 1e-12f));
      float ns = mean + sd * eps_s[t * DOUT + dd];
      xcur[dd] = ns;
      float rs = ns, cs = ns * ns;
      rs += __shfl_down(rs, 8);  cs += __shfl_down(cs, 8);
      rs += __shfl_down(rs, 4);  cs += __shfl_down(cs, 4);
      rs += __shfl_down(rs, 2);  cs += __shfl_down(cs, 2);
      rs += __shfl_down(rs, 1);  cs += __shfl_down(cs, 1);
      if (bid == 0){
        out[t * DOUT + dd]        = ns;
        out[1152 + t * DOUT + dd] = mean;
        out[2176 + t * DOUT + dd] = sd;
        if (dd == 0){ out[1024 + t] = rs; out[1088 + t] = cs; }
      }
    }
    __syncthreads();
  }
}

extern "C" void kernel_launch(void* const* d_in, const int* in_sizes, int n_in,
                              void* d_out, int out_size, void* d_ws, size_t ws_size,
                              hipStream_t stream) {
  (void)in_sizes; (void)n_in; (void)out_size; (void)ws_size;
  const float* xtr = (const float*)d_in[0];
  const float* ytr = (const float*)d_in[1];
  const float* ls  = (const float*)d_in[2];
  const float* var = (const float*)d_in[3];
  const float* noi = (const float*)d_in[4];
  const float* st0 = (const float*)d_in[5];
  const float* act = (const float*)d_in[6];
  const float* eps = (const float*)d_in[7];
  float* out = (float*)d_out;
  float* ws  = (float*)d_ws;
  void* args[] = { &xtr, &ytr, &ls, &var, &noi, &st0, &act, &eps, &out, &ws };
  hipLaunchCooperativeKernel((const void*)gp_rollout_kernel,
                             dim3(NBLK), dim3(NTHR), args, 0, stream);
}

// Round 4
// 1062.916 us; speedup vs baseline: 8.4379x; 1.8064x over previous
//
#include <hip/hip_runtime.h>
#include <hip/hip_fp16.h>
#include <hip/hip_cooperative_groups.h>

namespace cg = cooperative_groups;

#define N_TRAIN   2048
#define DOUT      16
#define DACT      8
#define DIN       24
#define HORIZON   64
#define JITTER    1e-6f

#define NBLK      256
#define NTHR      1024
#define RPB       8        // rows per block: 2048/256
#define SQS       2056     // fp16 sq LDS stride (16B-aligned rows)

#define POWER_ITERS 6
#define RICH_ITERS  10
#define MAXPC       18

// workspace layout (float indices)
#define OFF_PV0   0
#define OFF_PV1   32768
#define OFF_AA0   65536
#define OFF_AA1   98304
#define OFF_AL    131072
#define OFF_XT    163840               // xtrT [24][2048] fp32
#define OFF_RES   212992               // MAXPC frames * 6144 floats (48 slots * 8 lanes * 16f)
#define OFF_SYNC  (OFF_RES + MAXPC*6144)

__device__ __forceinline__ float fexp2(float x){ return __builtin_amdgcn_exp2f(x); }

__device__ __forceinline__ float bf2f(unsigned short u){
  union { unsigned int i; float f; } v; v.i = ((unsigned int)u) << 16; return v.f;
}
__device__ __forceinline__ unsigned short f2bf(float f){
  union { float f; unsigned int i; } v; v.f = f;
  unsigned int r = v.i + 0x7fffu + ((v.i >> 16) & 1u);
  return (unsigned short)(r >> 16);
}
__device__ __forceinline__ float aload(const float* p){
  unsigned int v = __hip_atomic_load((const unsigned int*)p, __ATOMIC_RELAXED,
                                     __HIP_MEMORY_SCOPE_AGENT);
  union { unsigned int u; float f; } c; c.u = v; return c.f;
}

// Flat grid barrier: arrivals spread over 8 cache lines (release-ordered, so
// prior stores/atomics are complete first). Wave 0 of every block polls all 8
// lines in ONE memory op (lanes 0-7), xor-reduces, uniform break. `spin=false`
// = arrive-only (for blocks that exit right after).
__device__ __forceinline__ void gbar(unsigned int* syn, int pc, bool spin){
  __syncthreads();
  if (threadIdx.x == 0){
    __threadfence();                       // release: write back dirty L2
    __hip_atomic_fetch_add(&syn[(blockIdx.x & 7) * 16], 1u,
                           __ATOMIC_RELEASE, __HIP_MEMORY_SCOPE_AGENT);
  }
  if (!spin) return;
  if (threadIdx.x < 64){
    const unsigned int target = (unsigned int)pc * NBLK;
    unsigned int* a = &syn[(threadIdx.x & 7) * 16];
    while (true){
      unsigned int v = (threadIdx.x < 8)
        ? __hip_atomic_load(a, __ATOMIC_RELAXED, __HIP_MEMORY_SCOPE_AGENT) : 0u;
      v += __shfl_xor(v, 1); v += __shfl_xor(v, 2); v += __shfl_xor(v, 4);
      if (__shfl(v, 0) >= target) break;
      __builtin_amdgcn_s_sleep(8);
    }
    if (threadIdx.x == 0) __threadfence(); // acquire: invalidate stale L1/L2
  }
  __syncthreads();
}

// w = G_d * u over this block's 8 rows; sq from LDS fp16 (16B vector reads).
__device__ __forceinline__ void sweep(const __half* sqh, const float* __restrict__ V,
                                      float ce, float gd, float* wfin,
                                      int rowbase, int d, int jg)
{
  float acc[RPB];
#pragma unroll
  for (int r = 0; r < RPB; ++r) acc[r] = 0.f;
#pragma unroll
  for (int seg = 0; seg < 4; ++seg){
    const int j0 = 8 * jg + 512 * seg;
    float4 ua = *reinterpret_cast<const float4*>(&V[d * N_TRAIN + j0]);
    float4 ub = *reinterpret_cast<const float4*>(&V[d * N_TRAIN + j0 + 4]);
    float u[8] = {ua.x, ua.y, ua.z, ua.w, ub.x, ub.y, ub.z, ub.w};
#pragma unroll
    for (int r = 0; r < RPB; ++r){
      uint4 sp = *reinterpret_cast<const uint4*>(&sqh[r * SQS + j0]);
      unsigned int w4[4] = {sp.x, sp.y, sp.z, sp.w};
#pragma unroll
      for (int e = 0; e < 4; ++e){
        __half2 h2 = *reinterpret_cast<const __half2*>(&w4[e]);
        float2 f2 = __half22float2(h2);
        acc[r] = fmaf(fexp2(ce * f2.x), u[2*e],   acc[r]);
        acc[r] = fmaf(fexp2(ce * f2.y), u[2*e+1], acc[r]);
      }
    }
  }
#pragma unroll
  for (int r = 0; r < RPB; ++r){
    acc[r] += __shfl_xor(acc[r], 1);
    acc[r] += __shfl_xor(acc[r], 2);
    acc[r] += __shfl_xor(acc[r], 4);
    acc[r] += __shfl_xor(acc[r], 8);
    acc[r] += __shfl_xor(acc[r], 16);
    acc[r] += __shfl_xor(acc[r], 32);
  }
  if (jg == 0){
#pragma unroll
    for (int r = 0; r < RPB; ++r){
      float ud = V[d * N_TRAIN + rowbase + r];
      wfin[r * 16 + d] = gd * (acc[r] - ud);   // subtract diagonal (sq=0 -> exp=1)
    }
  }
}

__global__ __launch_bounds__(NTHR, 1)
void gp_rollout_kernel(const float* __restrict__ xtr, const float* __restrict__ ytr,
                       const float* __restrict__ ls,  const float* __restrict__ var,
                       const float* __restrict__ noi, const float* __restrict__ st0,
                       const float* __restrict__ act, const float* __restrict__ eps,
                       float* __restrict__ out, float* __restrict__ ws)
{
  cg::grid_group grid = cg::this_grid();
  const int tid = threadIdx.x;
  const int bid = blockIdx.x;
  const int rowbase = bid * RPB;

  float* PV0  = ws + OFF_PV0;
  float* PV1  = ws + OFF_PV1;
  float* AA0  = ws + OFF_AA0;
  float* AA1  = ws + OFF_AA1;
  float* ALPH = ws + OFF_AL;
  float* XT   = ws + OFF_XT;
  float* RES  = ws + OFF_RES;
  unsigned int* syn = (unsigned int*)(ws + OFF_SYNC);

  // alv: rollout-stage bf16 {alpha, v} [2][16][2048] = 128 KB.
  // sqh (32.9 KB, precompute-only) ALIASES the front of alv — sqh is dead
  // before alv is first written (after the final precompute barrier).
  __shared__ unsigned short alv[2][DOUT][N_TRAIN];
  __half* sqh = reinterpret_cast<__half*>(&alv[0][0][0]);

  __shared__ float d2f[N_TRAIN];               // 8 KB
  __shared__ float act_s[HORIZON * DACT];      // 2 KB
  __shared__ float eps_s[HORIZON * DOUT];      // 4 KB
  __shared__ float pr[384];
  __shared__ float wfin[128];
  __shared__ float dsum[48];
  __shared__ float xcur[32];
  __shared__ float xrows[RPB * DIN];
  __shared__ float pv_s[128], v_s[128], yb_s[128];
  __shared__ float ce_s[16], g_s[16], s_s[16], var_s[16], nv_s[16];
  __shared__ float un_s[16], lam_s[16], sig_s[16], cb_s[16], ca_s[16];

  if (tid < 16){
    float l2 = ls[tid] * ls[tid];
    float nv = noi[tid] * noi[tid];
    float sd = var[tid] + nv + JITTER;
    ce_s[tid]  = -0.72134752044448f / l2;   // -0.5*log2(e)/ls^2
    g_s[tid]   = var[tid] / sd;
    s_s[tid]   = sd;
    var_s[tid] = var[tid];
    nv_s[tid]  = nv;
    un_s[tid]  = (float)N_TRAIN;            // ||ones||^2
  }
  if (tid < RPB * DIN) xrows[tid] = xtr[rowbase * DIN + tid];
  if (tid < HORIZON * DACT) act_s[tid] = act[tid];
  if (tid < HORIZON * DOUT) eps_s[tid] = eps[tid];
  __syncthreads();

  // -------- Phase 0: sq rows -> LDS fp16; xtrT; caches; zero RES+sync -------
  if (tid < 128){
    const int dd = tid >> 3, r = tid & 7;
    yb_s[tid] = ytr[(rowbase + r) * DOUT + dd] / s_s[dd];
    PV0[dd * N_TRAIN + rowbase + r] = 1.0f;
    pv_s[tid] = 1.0f;
  }
  {
    const int r  = tid >> 7;      // 0..7, 128 threads per row
    const int c0 = tid & 127;
    float xl[DIN];
#pragma unroll
    for (int k = 0; k < DIN; ++k) xl[k] = xrows[r * DIN + k];
    for (int q = 0; q < 16; ++q){
      const int j = c0 + (q << 7);
      const float4* xp = reinterpret_cast<const float4*>(xtr + j * DIN);
      float sacc = 0.f;
#pragma unroll
      for (int v4 = 0; v4 < 6; ++v4){
        float4 x4 = xp[v4];
        float e0 = xl[v4*4+0] - x4.x, e1 = xl[v4*4+1] - x4.y;
        float e2 = xl[v4*4+2] - x4.z, e3 = xl[v4*4+3] - x4.w;
        sacc = fmaf(e0,e0, fmaf(e1,e1, fmaf(e2,e2, fmaf(e3,e3, sacc))));
      }
      sqh[r * SQS + j] = __float2half_rn(sacc);
    }
  }
  if (tid < RPB * DIN){
    int r = tid / DIN, k = tid % DIN;
    XT[k * N_TRAIN + rowbase + r] = xrows[r * DIN + k];
  }
  {
    int i = bid * NTHR + tid;
    if (i < MAXPC * 6144) RES[i] = 0.f;
  }
  if (bid == 0 && tid < 128) syn[tid] = 0u;
  __syncthreads();
  __threadfence();
  grid.sync();            // single cooperative sync: init visibility everywhere
  int pc = 0;

  const int d  = tid >> 6;   // 0..15, one wave per output
  const int jg = tid & 63;
  const int lane8 = bid & 7;

  // -------- Power iteration --------------------------------------------------
  float* PVc = PV0; float* PVn = PV1;
#pragma unroll 1
  for (int it = 0; it < POWER_ITERS; ++it){
    const bool last = (it == POWER_ITERS - 1);
    sweep(sqh, PVc, ce_s[d], g_s[d], wfin, rowbase, d, jg);
    __syncthreads();
    if (tid < 128){
      const int dd = tid >> 3, r = tid & 7, rowg = rowbase + r;
      float w = wfin[r * 16 + dd];
      PVn[dd * N_TRAIN + rowg] = w;
      float u = pv_s[tid];
      pv_s[tid] = w;
      pr[tid]       = w * w;
      pr[128 + tid] = u * w;
      pr[256 + tid] = last ? yb_s[tid] * w : 0.f;
    }
    __syncthreads();
    ++pc;
    if (tid < 48){
      const int slot = tid >> 4, dd = tid & 15;
      float s = 0.f;
#pragma unroll
      for (int r = 0; r < 8; ++r) s += pr[slot * 128 + dd * 8 + r];
      atomicAdd(&RES[pc * 6144 + (tid * 8 + lane8) * 16], s);
    }
    gbar(syn, pc, true);
    if (tid < 48){
      const float* base = &RES[pc * 6144 + tid * 128];
      float s = 0.f;
#pragma unroll
      for (int l = 0; l < 8; ++l) s += aload(base + l * 16);
      dsum[tid] = s;
    }
    __syncthreads();
    if (tid < 16){
      float ww = dsum[tid];        // slot0: w.w
      float uw = dsum[16 + tid];   // slot1: u.w
      if (last){
        lam_s[tid] = uw / fmaxf(un_s[tid], 1e-30f);   // Rayleigh quotient
        float sg = rsqrtf(fmaxf(ww, 1e-38f));
        sig_s[tid] = sg;
        cb_s[tid]  = sg * dsum[32 + tid];              // v1^T (y/s)
      }
      un_s[tid] = ww;
    }
    __syncthreads();
    float* tmp = PVc; PVc = PVn; PVn = tmp;
  }

  // -------- a0 = b - cb*v1 ; analytically v^T a0 = 0 -------------------------
  if (tid < 128){
    const int dd = tid >> 3, r = tid & 7, rowg = rowbase + r;
    float v = sig_s[dd] * pv_s[tid];
    v_s[tid] = v;
    AA0[dd * N_TRAIN + rowg] = yb_s[tid] - cb_s[dd] * v;
  }
  if (tid < 16) ca_s[tid] = 0.f;                 // v unit => v^T a0 = cb - cb = 0
  ++pc;
  gbar(syn, pc, true);                           // visibility of AA0

  // -------- Richardson on deflated operator ----------------------------------
  float* Ac = AA0; float* An = AA1;
#pragma unroll 1
  for (int it = 0; it < RICH_ITERS; ++it){
    const bool last = (it == RICH_ITERS - 1);
    sweep(sqh, Ac, ce_s[d], g_s[d], wfin, rowbase, d, jg);
    __syncthreads();
    if (tid < 128){
      const int dd = tid >> 3, r = tid & 7, rowg = rowbase + r;
      float w = wfin[r * 16 + dd];
      float v = v_s[tid];
      float bperp = yb_s[tid] - cb_s[dd] * v;
      float anew = bperp - (w - lam_s[dd] * ca_s[dd] * v);
      if (last){
        ALPH[dd * N_TRAIN + rowg] = anew + (cb_s[dd] / (1.f + lam_s[dd])) * v;
      } else {
        An[dd * N_TRAIN + rowg] = anew;
        pr[tid] = v * anew;
      }
    }
    __syncthreads();
    ++pc;
    if (last){
      gbar(syn, pc, bid == 0);   // blocks != 0: arrive-only, then exit
      if (bid != 0) return;
      break;
    }
    if (tid < 16){
      float s = 0.f;
#pragma unroll
      for (int r = 0; r < 8; ++r) s += pr[tid * 8 + r];
      atomicAdd(&RES[pc * 6144 + (tid * 8 + lane8) * 16], s);
    }
    gbar(syn, pc, true);
    if (tid < 16){
      const float* base = &RES[pc * 6144 + tid * 128];
      float s = 0.f;
#pragma unroll
      for (int l = 0; l < 8; ++l) s += aload(base + l * 16);
      ca_s[tid] = s;
    }
    __syncthreads();
    float* tmp = Ac; Ac = An; An = tmp;
  }

  // ======== Rollout: SINGLE BLOCK (bid 0), no grid barriers ==================
  // Stage alpha and v to LDS bf16 (acquire fence at the final barrier made
  // ALPH/PVc globally fresh). sqh is dead from here on (aliased by alv).
  for (int i = tid; i < DOUT * N_TRAIN; i += NTHR){
    const int dd = i >> 11, j = i & (N_TRAIN - 1);
    alv[0][dd][j] = f2bf(ALPH[dd * N_TRAIN + j]);
    alv[1][dd][j] = f2bf(sig_s[dd] * PVc[dd * N_TRAIN + j]);
  }
  if (tid < 16) xcur[tid] = st0[tid];
  __syncthreads();

  const float2* XT2 = reinterpret_cast<const float2*>(XT);

#pragma unroll 1
  for (int t = 0; t < HORIZON; ++t){
    if (tid >= 16 && tid < 24) xcur[tid] = act_s[t * DACT + (tid - 16)];
    __syncthreads();
    // d2 to all training points (XT is L2-resident on this XCD)
    {
      float xl[DIN];
#pragma unroll
      for (int k = 0; k < DIN; ++k) xl[k] = xcur[k];
      float sx = 0.f, sy = 0.f;
#pragma unroll
      for (int k = 0; k < DIN; ++k){
        float2 xv = XT2[k * (N_TRAIN / 2) + tid];
        float e0 = xl[k] - xv.x, e1 = xl[k] - xv.y;
        sx = fmaf(e0, e0, sx); sy = fmaf(e1, e1, sy);
      }
      *reinterpret_cast<float2*>(&d2f[2 * tid]) = make_float2(sx, sy);
    }
    __syncthreads();
    // dots: mean = k.alpha, c = k.v, kk = k.k  (wave d handles output d)
    {
      const float ced = ce_s[d], vd = var_s[d];
      float am = 0.f, ac = 0.f, ak = 0.f;
#pragma unroll
      for (int q = 0; q < 16; ++q){
        const int j = 2 * jg + (q << 7);
        float2 dj = *reinterpret_cast<const float2*>(&d2f[j]);
        unsigned int ua = *reinterpret_cast<const unsigned int*>(&alv[0][d][j]);
        unsigned int uv = *reinterpret_cast<const unsigned int*>(&alv[1][d][j]);
        float k0 = vd * fexp2(ced * dj.x);
        float k1 = vd * fexp2(ced * dj.y);
        am = fmaf(k0, bf2f((unsigned short)(ua & 0xffffu)), am);
        am = fmaf(k1, bf2f((unsigned short)(ua >> 16)), am);
        ac = fmaf(k0, bf2f((unsigned short)(uv & 0xffffu)), ac);
        ac = fmaf(k1, bf2f((unsigned short)(uv >> 16)), ac);
        ak = fmaf(k0, k0, ak);
        ak = fmaf(k1, k1, ak);
      }
#pragma unroll
      for (int off = 1; off < 64; off <<= 1){
        am += __shfl_xor(am, off);
        ac += __shfl_xor(ac, off);
        ak += __shfl_xor(ak, off);
      }
      if (jg == 0){ pr[d] = am; pr[16 + d] = ac; pr[32 + d] = ak; }
    }
    __syncthreads();
    if (tid < 16){
      const int dd = tid;
      float mean = pr[dd], c = pr[16 + dd], kk = pr[32 + dd];
      float lam = lam_s[dd];
      float qs = c * c / (1.f + lam) + (kk - c * c);   // k^T Ky^-1 k * s
      float q  = qs / s_s[dd];
      float pvv = var_s[dd] - q + nv_s[dd];
      float sd = sqrtf(fmaxf(pvv, 1e-12f));
      float ns = mean + sd * eps_s[t * DOUT + dd];
      xcur[dd] = ns;
      float rs = ns, cs = ns * ns;
      rs += __shfl_down(rs, 8);  cs += __shfl_down(cs, 8);
      rs += __shfl_down(rs, 4);  cs += __shfl_down(cs, 4);
      rs += __shfl_down(rs, 2);  cs += __shfl_down(cs, 2);
      rs += __shfl_down(rs, 1);  cs += __shfl_down(cs, 1);
      out[t * DOUT + dd]        = ns;     // trajectory
      out[1152 + t * DOUT + dd] = mean;   // means
      out[2176 + t * DOUT + dd] = sd;     // stds
      if (dd == 0){ out[1024 + t] = rs; out[1088 + t] = cs; }  // reward, cost
    }
    __syncthreads();
  }
}

extern "C" void kernel_launch(void* const* d_in, const int* in_sizes, int n_in,
                              void* d_out, int out_size, void* d_ws, size_t ws_size,
                              hipStream_t stream) {
  (void)in_sizes; (void)n_in; (void)out_size; (void)ws_size;
  const float* xtr = (const float*)d_in[0];
  const float* ytr = (const float*)d_in[1];
  const float* ls  = (const float*)d_in[2];
  const float* var = (const float*)d_in[3];
  const float* noi = (const float*)d_in[4];
  const float* st0 = (const float*)d_in[5];
  const float* act = (const float*)d_in[6];
  const float* eps = (const float*)d_in[7];
  float* out = (float*)d_out;
  float* ws  = (float*)d_ws;
  void* args[] = { &xtr, &ytr, &ls, &var, &noi, &st0, &act, &eps, &out, &ws };
  hipLaunchCooperativeKernel((const void*)gp_rollout_kernel,
                             dim3(NBLK), dim3(NTHR), args, 0, stream);
}

// Round 5
// 663.234 us; speedup vs baseline: 13.5228x; 1.6026x over previous
//
#include <hip/hip_runtime.h>
#include <hip/hip_fp16.h>
#include <hip/hip_cooperative_groups.h>

namespace cg = cooperative_groups;

#define N_TRAIN   2048
#define DOUT      16
#define DACT      8
#define DIN       24
#define HORIZON   64
#define JITTER    1e-6f

#define NBLK      256
#define NTHR      1024
#define RPB       8        // rows per block: 2048/256
#define SQS       2056     // fp16 sq LDS stride (16B-aligned rows)
#define NROLL     16       // rollout blocks, one GP output each

#define POWER_ITERS 6
#define RICH_ITERS  10
#define MAXPC       18

// workspace layout (float indices)
#define OFF_PV0   0
#define OFF_PV1   32768
#define OFF_AA0   65536
#define OFF_AA1   98304
#define OFF_AL    131072
#define OFF_RES   163840                    // MAXPC frames * 6144 floats
#define OFF_SYN   (OFF_RES + MAXPC*6144)    // u32 region: 8 arrival + 8 gen lines + rctr
#define OFF_RES2  (OFF_SYN + 1024)          // 64 steps * 64 floats

__device__ __forceinline__ float fexp2(float x){ return __builtin_amdgcn_exp2f(x); }

// MALL-direct (agent-scope, L2-bypass) accessors. All cross-block traffic goes
// through these -> no fences, no L2 invalidation, caches stay hot.
__device__ __forceinline__ float aload(const float* p){
  unsigned int v = __hip_atomic_load((const unsigned int*)p, __ATOMIC_RELAXED,
                                     __HIP_MEMORY_SCOPE_AGENT);
  union { unsigned int u; float f; } c; c.u = v; return c.f;
}
__device__ __forceinline__ float2 aload2(const float* p){
  unsigned long long v = __hip_atomic_load((const unsigned long long*)p,
                                           __ATOMIC_RELAXED, __HIP_MEMORY_SCOPE_AGENT);
  union { unsigned long long u; float2 f; } c; c.u = v; return c.f;
}
__device__ __forceinline__ void astore(float* p, float v){
  union { float f; unsigned int u; } c; c.f = v;
  __hip_atomic_store((unsigned int*)p, c.u, __ATOMIC_RELAXED, __HIP_MEMORY_SCOPE_AGENT);
}

// Two-level fence-free grid barrier. Arrivals: release-RMW on 8 lines (orders
// prior MALL stores). Block 0 detects full count, publishes pc to 8 gen lines;
// followers poll their own gen line. spin=false: arrive-only (block exits next).
__device__ __forceinline__ void gbar_pre(unsigned int* syn, int pc, bool spin){
  __syncthreads();
  if (threadIdx.x == 0){
    __hip_atomic_fetch_add(&syn[(blockIdx.x & 7) * 16], 1u,
                           __ATOMIC_RELEASE, __HIP_MEMORY_SCOPE_AGENT);
  }
  if (!spin) return;
  if (blockIdx.x == 0){
    if (threadIdx.x < 64){
      const unsigned int target = (unsigned int)pc * NBLK;
      while (true){
        unsigned int v = (threadIdx.x < 8)
          ? __hip_atomic_load(&syn[threadIdx.x * 16], __ATOMIC_RELAXED,
                              __HIP_MEMORY_SCOPE_AGENT) : 0u;
        v += __shfl_xor(v, 1); v += __shfl_xor(v, 2); v += __shfl_xor(v, 4);
        if (__shfl(v, 0) >= target) break;
        __builtin_amdgcn_s_sleep(2);
      }
      if (threadIdx.x < 8)
        __hip_atomic_store(&syn[128 + threadIdx.x * 16], (unsigned int)pc,
                           __ATOMIC_RELAXED, __HIP_MEMORY_SCOPE_AGENT);
    }
  } else if (threadIdx.x == 0){
    unsigned int* g = &syn[128 + (blockIdx.x & 7) * 16];
    while (__hip_atomic_load(g, __ATOMIC_RELAXED, __HIP_MEMORY_SCOPE_AGENT)
           < (unsigned int)pc){
      __builtin_amdgcn_s_sleep(8);
    }
  }
  __syncthreads();
}

// Flat 16-block rollout barrier: single line, release arrivals, relaxed polls.
__device__ __forceinline__ void gbar_roll(unsigned int* rctr, unsigned int target){
  __syncthreads();
  if (threadIdx.x == 0){
    __hip_atomic_fetch_add(rctr, 1u, __ATOMIC_RELEASE, __HIP_MEMORY_SCOPE_AGENT);
    while (__hip_atomic_load(rctr, __ATOMIC_RELAXED, __HIP_MEMORY_SCOPE_AGENT)
           < target){
      __builtin_amdgcn_s_sleep(2);
    }
  }
  __syncthreads();
}

// w = G_d * u over this block's 8 rows; sq from LDS fp16; V via MALL 8B loads.
__device__ __forceinline__ void sweep(const __half* sqh, const float* __restrict__ V,
                                      float ce, float gd, float* wfin,
                                      int rowbase, int d, int jg)
{
  float acc[RPB];
#pragma unroll
  for (int r = 0; r < RPB; ++r) acc[r] = 0.f;
#pragma unroll
  for (int seg = 0; seg < 4; ++seg){
    const int j0 = 8 * jg + 512 * seg;
    float2 u01 = aload2(&V[d * N_TRAIN + j0]);
    float2 u23 = aload2(&V[d * N_TRAIN + j0 + 2]);
    float2 u45 = aload2(&V[d * N_TRAIN + j0 + 4]);
    float2 u67 = aload2(&V[d * N_TRAIN + j0 + 6]);
    float u[8] = {u01.x, u01.y, u23.x, u23.y, u45.x, u45.y, u67.x, u67.y};
#pragma unroll
    for (int r = 0; r < RPB; ++r){
      uint4 sp = *reinterpret_cast<const uint4*>(&sqh[r * SQS + j0]);
      unsigned int w4[4] = {sp.x, sp.y, sp.z, sp.w};
#pragma unroll
      for (int e = 0; e < 4; ++e){
        __half2 h2 = *reinterpret_cast<const __half2*>(&w4[e]);
        float2 f2 = __half22float2(h2);
        acc[r] = fmaf(fexp2(ce * f2.x), u[2*e],   acc[r]);
        acc[r] = fmaf(fexp2(ce * f2.y), u[2*e+1], acc[r]);
      }
    }
  }
#pragma unroll
  for (int r = 0; r < RPB; ++r){
    acc[r] += __shfl_xor(acc[r], 1);
    acc[r] += __shfl_xor(acc[r], 2);
    acc[r] += __shfl_xor(acc[r], 4);
    acc[r] += __shfl_xor(acc[r], 8);
    acc[r] += __shfl_xor(acc[r], 16);
    acc[r] += __shfl_xor(acc[r], 32);
  }
  if (jg == 0){
#pragma unroll
    for (int r = 0; r < RPB; ++r){
      float ud = aload(&V[d * N_TRAIN + rowbase + r]);
      wfin[r * 16 + d] = gd * (acc[r] - ud);   // subtract diagonal (sq=0 -> exp=1)
    }
  }
}

__global__ __launch_bounds__(NTHR, 1)
void gp_rollout_kernel(const float* __restrict__ xtr, const float* __restrict__ ytr,
                       const float* __restrict__ ls,  const float* __restrict__ var,
                       const float* __restrict__ noi, const float* __restrict__ st0,
                       const float* __restrict__ act, const float* __restrict__ eps,
                       float* __restrict__ out, float* __restrict__ ws)
{
  cg::grid_group grid = cg::this_grid();
  const int tid = threadIdx.x;
  const int bid = blockIdx.x;
  const int rowbase = bid * RPB;

  float* PV0  = ws + OFF_PV0;
  float* PV1  = ws + OFF_PV1;
  float* AA0  = ws + OFF_AA0;
  float* AA1  = ws + OFF_AA1;
  float* ALPH = ws + OFF_AL;
  float* RES  = ws + OFF_RES;
  float* RES2 = ws + OFF_RES2;
  unsigned int* syn = (unsigned int*)(ws + OFF_SYN);
  unsigned int* rctr = &syn[256];

  __shared__ __half sqh[RPB * SQS];            // 32.9 KB
  __shared__ float act_s[HORIZON * DACT];      // 2 KB
  __shared__ float eps_s[HORIZON * DOUT];      // 4 KB
  __shared__ float pr[384];
  __shared__ float wfin[128];
  __shared__ float dsum[48];
  __shared__ float xcur[32];
  __shared__ float xrows[RPB * DIN];
  __shared__ float pv_s[128], v_s[128], yb_s[128];
  __shared__ float ce_s[16], g_s[16], s_s[16], var_s[16], nv_s[16];
  __shared__ float un_s[16], lam_s[16], sig_s[16], cb_s[16], ca_s[16];

  if (tid < 16){
    float l2 = ls[tid] * ls[tid];
    float nv = noi[tid] * noi[tid];
    float sd = var[tid] + nv + JITTER;
    ce_s[tid]  = -0.72134752044448f / l2;   // -0.5*log2(e)/ls^2
    g_s[tid]   = var[tid] / sd;
    s_s[tid]   = sd;
    var_s[tid] = var[tid];
    nv_s[tid]  = nv;
    un_s[tid]  = (float)N_TRAIN;            // ||ones||^2
  }
  if (tid < RPB * DIN) xrows[tid] = xtr[rowbase * DIN + tid];
  if (tid < HORIZON * DACT) act_s[tid] = act[tid];
  if (tid < HORIZON * DOUT) eps_s[tid] = eps[tid];
  __syncthreads();

  // -------- Phase 0: sq rows -> LDS fp16; caches; zero RES + sync lines -----
  if (tid < 128){
    const int dd = tid >> 3, r = tid & 7;
    yb_s[tid] = ytr[(rowbase + r) * DOUT + dd] / s_s[dd];
    astore(&PV0[dd * N_TRAIN + rowbase + r], 1.0f);
    pv_s[tid] = 1.0f;
  }
  {
    const int r  = tid >> 7;      // 0..7, 128 threads per row
    const int c0 = tid & 127;
    float xl[DIN];
#pragma unroll
    for (int k = 0; k < DIN; ++k) xl[k] = xrows[r * DIN + k];
    for (int q = 0; q < 16; ++q){
      const int j = c0 + (q << 7);
      const float4* xp = reinterpret_cast<const float4*>(xtr + j * DIN);
      float sacc = 0.f;
#pragma unroll
      for (int v4 = 0; v4 < 6; ++v4){
        float4 x4 = xp[v4];
        float e0 = xl[v4*4+0] - x4.x, e1 = xl[v4*4+1] - x4.y;
        float e2 = xl[v4*4+2] - x4.z, e3 = xl[v4*4+3] - x4.w;
        sacc = fmaf(e0,e0, fmaf(e1,e1, fmaf(e2,e2, fmaf(e3,e3, sacc))));
      }
      sqh[r * SQS + j] = __float2half_rn(sacc);
    }
  }
  {
    int i = bid * NTHR + tid;
    if (i < MAXPC * 6144) RES[i] = 0.f;
  }
  if (bid == 0 && tid < 512) syn[tid] = 0u;
  __syncthreads();
  __threadfence();
  grid.sync();            // single cooperative sync: init visibility everywhere
  int pc = 0;

  const int d  = tid >> 6;   // 0..15, one wave per output
  const int jg = tid & 63;
  const int lane8 = bid & 7;

  // -------- Power iteration --------------------------------------------------
  float* PVc = PV0; float* PVn = PV1;
#pragma unroll 1
  for (int it = 0; it < POWER_ITERS; ++it){
    const bool last = (it == POWER_ITERS - 1);
    sweep(sqh, PVc, ce_s[d], g_s[d], wfin, rowbase, d, jg);
    __syncthreads();
    if (tid < 128){
      const int dd = tid >> 3, r = tid & 7, rowg = rowbase + r;
      float w = wfin[r * 16 + dd];
      astore(&PVn[dd * N_TRAIN + rowg], w);
      float u = pv_s[tid];
      pv_s[tid] = w;
      pr[tid]       = w * w;
      pr[128 + tid] = u * w;
      pr[256 + tid] = last ? yb_s[tid] * w : 0.f;
    }
    __syncthreads();
    ++pc;
    if (tid < 48){
      const int slot = tid >> 4, dd = tid & 15;
      float s = 0.f;
#pragma unroll
      for (int r = 0; r < 8; ++r) s += pr[slot * 128 + dd * 8 + r];
      atomicAdd(&RES[pc * 6144 + (tid * 8 + lane8) * 16], s);
    }
    gbar_pre(syn, pc, true);
    if (tid < 48){
      const float* base = &RES[pc * 6144 + tid * 128];
      float s = 0.f;
#pragma unroll
      for (int l = 0; l < 8; ++l) s += aload(base + l * 16);
      dsum[tid] = s;
    }
    __syncthreads();
    if (tid < 16){
      float ww = dsum[tid];        // slot0: w.w
      float uw = dsum[16 + tid];   // slot1: u.w
      if (last){
        lam_s[tid] = uw / fmaxf(un_s[tid], 1e-30f);   // Rayleigh quotient
        float sg = rsqrtf(fmaxf(ww, 1e-38f));
        sig_s[tid] = sg;
        cb_s[tid]  = sg * dsum[32 + tid];              // v1^T (y/s)
      }
      un_s[tid] = ww;
    }
    __syncthreads();
    float* tmp = PVc; PVc = PVn; PVn = tmp;
  }

  // -------- a0 = b - cb*v1 ; analytically v^T a0 = 0 -------------------------
  if (tid < 128){
    const int dd = tid >> 3, r = tid & 7, rowg = rowbase + r;
    float v = sig_s[dd] * pv_s[tid];
    v_s[tid] = v;
    astore(&AA0[dd * N_TRAIN + rowg], yb_s[tid] - cb_s[dd] * v);
  }
  if (tid < 16) ca_s[tid] = 0.f;                 // v unit => v^T a0 = cb - cb = 0
  ++pc;
  gbar_pre(syn, pc, true);                       // visibility of AA0

  // -------- Richardson on deflated operator ----------------------------------
  float* Ac = AA0; float* An = AA1;
#pragma unroll 1
  for (int it = 0; it < RICH_ITERS; ++it){
    const bool last = (it == RICH_ITERS - 1);
    sweep(sqh, Ac, ce_s[d], g_s[d], wfin, rowbase, d, jg);
    __syncthreads();
    if (tid < 128){
      const int dd = tid >> 3, r = tid & 7, rowg = rowbase + r;
      float w = wfin[r * 16 + dd];
      float v = v_s[tid];
      float bperp = yb_s[tid] - cb_s[dd] * v;
      float anew = bperp - (w - lam_s[dd] * ca_s[dd] * v);
      if (last){
        astore(&ALPH[dd * N_TRAIN + rowg], anew + (cb_s[dd] / (1.f + lam_s[dd])) * v);
      } else {
        astore(&An[dd * N_TRAIN + rowg], anew);
        pr[tid] = v * anew;
      }
    }
    __syncthreads();
    ++pc;
    if (last){
      gbar_pre(syn, pc, bid < NROLL);   // blocks >= NROLL: arrive-only, exit
      if (bid >= NROLL) return;
      break;
    }
    if (tid < 16){
      float s = 0.f;
#pragma unroll
      for (int r = 0; r < 8; ++r) s += pr[tid * 8 + r];
      atomicAdd(&RES[pc * 6144 + (tid * 8 + lane8) * 16], s);
    }
    gbar_pre(syn, pc, true);
    if (tid < 16){
      const float* base = &RES[pc * 6144 + tid * 128];
      float s = 0.f;
#pragma unroll
      for (int l = 0; l < 8; ++l) s += aload(base + l * 16);
      ca_s[tid] = s;
    }
    __syncthreads();
    float* tmp = Ac; Ac = An; An = tmp;
  }

  // ======== Rollout: NROLL blocks, one output each, 1 barrier/step ===========
  const int dd_own = bid;
  const float ced = ce_s[dd_own], vd = var_s[dd_own];

  // fp32 alpha/v for this thread's two training points (registers, no LDS)
  const int p0 = 2 * tid, p1 = 2 * tid + 1;
  float a0r = aload(&ALPH[dd_own * N_TRAIN + p0]);
  float a1r = aload(&ALPH[dd_own * N_TRAIN + p1]);
  float v0r = sig_s[dd_own] * aload(&PVc[dd_own * N_TRAIN + p0]);
  float v1r = sig_s[dd_own] * aload(&PVc[dd_own * N_TRAIN + p1]);

  // this thread's two training points, fp32 in registers
  float xp0[DIN], xp1[DIN];
#pragma unroll
  for (int k = 0; k < DIN; ++k){
    xp0[k] = xtr[p0 * DIN + k];
    xp1[k] = xtr[p1 * DIN + k];
  }
  if (tid < 16) xcur[tid] = st0[tid];
  __syncthreads();

#pragma unroll 1
  for (int t = 0; t < HORIZON; ++t){
    if (tid >= 16 && tid < 24) xcur[tid] = act_s[t * DACT + (tid - 16)];
    __syncthreads();
    // d2 in registers (xcur LDS reads are uniform broadcasts)
    float sx = 0.f, sy = 0.f;
#pragma unroll
    for (int k = 0; k < DIN; ++k){
      float xc = xcur[k];
      float e0 = xc - xp0[k], e1 = xc - xp1[k];
      sx = fmaf(e0, e0, sx); sy = fmaf(e1, e1, sy);
    }
    // dots for this block's output
    float k0 = vd * fexp2(ced * sx);
    float k1 = vd * fexp2(ced * sy);
    float am = fmaf(k0, a0r, k1 * a1r);
    float ac = fmaf(k0, v0r, k1 * v1r);
    float ak = fmaf(k0, k0,  k1 * k1);
#pragma unroll
    for (int off = 1; off < 64; off <<= 1){
      am += __shfl_xor(am, off);
      ac += __shfl_xor(ac, off);
      ak += __shfl_xor(ak, off);
    }
    if ((tid & 63) == 0){
      const int wv = tid >> 6;
      pr[wv * 3 + 0] = am; pr[wv * 3 + 1] = ac; pr[wv * 3 + 2] = ak;
    }
    __syncthreads();
    if (tid < 3){
      float s = 0.f;
#pragma unroll
      for (int w = 0; w < 16; ++w) s += pr[w * 3 + tid];
      astore(&RES2[t * 64 + dd_own * 3 + tid], s);
    }
    gbar_roll(rctr, (unsigned int)(t + 1) * NROLL);
    if (tid < 48) dsum[tid] = aload(&RES2[t * 64 + tid]);
    __syncthreads();
    if (tid < 16){
      const int dd = tid;
      float mean = dsum[3*dd], c = dsum[3*dd+1], kk = dsum[3*dd+2];
      float lam = lam_s[dd];
      float qs = c * c / (1.f + lam) + (kk - c * c);   // k^T Ky^-1 k * s
      float q  = qs / s_s[dd];
      float pvv = var_s[dd] - q + nv_s[dd];
      float sd = sqrtf(fmaxf(pvv, 1e-12f));
      float ns = mean + sd * eps_s[t * DOUT + dd];
      xcur[dd] = ns;                     // identical in every block
      float rs = ns, cs = ns * ns;
      rs += __shfl_down(rs, 8);  cs += __shfl_down(cs, 8);
      rs += __shfl_down(rs, 4);  cs += __shfl_down(cs, 4);
      rs += __shfl_down(rs, 2);  cs += __shfl_down(cs, 2);
      rs += __shfl_down(rs, 1);  cs += __shfl_down(cs, 1);
      if (bid == 0){
        out[t * DOUT + dd]        = ns;     // trajectory
        out[1152 + t * DOUT + dd] = mean;   // means
        out[2176 + t * DOUT + dd] = sd;     // stds
        if (dd == 0){ out[1024 + t] = rs; out[1088 + t] = cs; }  // reward, cost
      }
    }
    __syncthreads();
  }
}

extern "C" void kernel_launch(void* const* d_in, const int* in_sizes, int n_in,
                              void* d_out, int out_size, void* d_ws, size_t ws_size,
                              hipStream_t stream) {
  (void)in_sizes; (void)n_in; (void)out_size; (void)ws_size;
  const float* xtr = (const float*)d_in[0];
  const float* ytr = (const float*)d_in[1];
  const float* ls  = (const float*)d_in[2];
  const float* var = (const float*)d_in[3];
  const float* noi = (const float*)d_in[4];
  const float* st0 = (const float*)d_in[5];
  const float* act = (const float*)d_in[6];
  const float* eps = (const float*)d_in[7];
  float* out = (float*)d_out;
  float* ws  = (float*)d_ws;
  void* args[] = { &xtr, &ytr, &ls, &var, &noi, &st0, &act, &eps, &out, &ws };
  hipLaunchCooperativeKernel((const void*)gp_rollout_kernel,
                             dim3(NBLK), dim3(NTHR), args, 0, stream);
}

// Round 8
// 657.670 us; speedup vs baseline: 13.6372x; 1.0085x over previous
//
#include <hip/hip_runtime.h>
#include <hip/hip_fp16.h>
#include <hip/hip_cooperative_groups.h>

namespace cg = cooperative_groups;

#define N_TRAIN   2048
#define DOUT      16
#define DACT      8
#define DIN       24
#define HORIZON   64
#define JITTER    1e-6f

#define NBLK      256
#define NTHR      1024
#define RPB       8        // rows per block: 2048/256
#define SQS       2056     // fp16 sq LDS stride (16B-aligned rows)
#define NROLL     16       // rollout blocks, one GP output each

#define POWER_ITERS 6
#define RICH_ITERS  10
#define MAXPC       18

// workspace layout (float indices) — r5 layout verbatim
#define OFF_PV0   0
#define OFF_PV1   32768
#define OFF_AA0   65536
#define OFF_AA1   98304
#define OFF_AL    131072
#define OFF_RES   163840                    // MAXPC frames * 6144 floats
#define OFF_SYN   (OFF_RES + MAXPC*6144)    // u32: 8 arrival lines + 8 gen lines
#define OFF_RES2  (OFF_SYN + 1024)          // 64 steps * 64 float2 (value,tag)

__device__ __forceinline__ float fexp2(float x){ return __builtin_amdgcn_exp2f(x); }

// MALL-direct (agent-scope, relaxed) accessors — no fences, L2 never invalidated.
__device__ __forceinline__ float aload(const float* p){
  unsigned int v = __hip_atomic_load((const unsigned int*)p, __ATOMIC_RELAXED,
                                     __HIP_MEMORY_SCOPE_AGENT);
  union { unsigned int u; float f; } c; c.u = v; return c.f;
}
__device__ __forceinline__ float2 aload2(const float* p){
  unsigned long long v = __hip_atomic_load((const unsigned long long*)p,
                                           __ATOMIC_RELAXED, __HIP_MEMORY_SCOPE_AGENT);
  union { unsigned long long u; float2 f; } c; c.u = v; return c.f;
}
__device__ __forceinline__ void astore(float* p, float v){
  union { float f; unsigned int u; } c; c.f = v;
  __hip_atomic_store((unsigned int*)p, c.u, __ATOMIC_RELAXED, __HIP_MEMORY_SCOPE_AGENT);
}
__device__ __forceinline__ void astore2(float* p, float2 v){
  union { float2 f; unsigned long long u; } c; c.f = v;
  __hip_atomic_store((unsigned long long*)p, c.u, __ATOMIC_RELAXED,
                     __HIP_MEMORY_SCOPE_AGENT);
}

// Two-level fence-free grid barrier (precompute only) — r5 verbatim.
__device__ __forceinline__ void gbar_pre(unsigned int* syn, int pc, bool spin){
  __syncthreads();
  if (threadIdx.x == 0){
    __hip_atomic_fetch_add(&syn[(blockIdx.x & 7) * 16], 1u,
                           __ATOMIC_RELEASE, __HIP_MEMORY_SCOPE_AGENT);
  }
  if (!spin) return;
  if (blockIdx.x == 0){
    if (threadIdx.x < 64){
      const unsigned int target = (unsigned int)pc * NBLK;
      while (true){
        unsigned int v = (threadIdx.x < 8)
          ? __hip_atomic_load(&syn[threadIdx.x * 16], __ATOMIC_RELAXED,
                              __HIP_MEMORY_SCOPE_AGENT) : 0u;
        v += __shfl_xor(v, 1); v += __shfl_xor(v, 2); v += __shfl_xor(v, 4);
        if (__shfl(v, 0) >= target) break;
        __builtin_amdgcn_s_sleep(1);
      }
      if (threadIdx.x < 8)
        __hip_atomic_store(&syn[128 + threadIdx.x * 16], (unsigned int)pc,
                           __ATOMIC_RELAXED, __HIP_MEMORY_SCOPE_AGENT);
    }
  } else if (threadIdx.x == 0){
    unsigned int* g = &syn[128 + (blockIdx.x & 7) * 16];
    while (__hip_atomic_load(g, __ATOMIC_RELAXED, __HIP_MEMORY_SCOPE_AGENT)
           < (unsigned int)pc){
      __builtin_amdgcn_s_sleep(2);
    }
  }
  __syncthreads();
}

// w = G_d * u over this block's 8 rows; sq from LDS fp16 — r5 verbatim.
__device__ __forceinline__ void sweep(const __half* sqh, const float* __restrict__ V,
                                      float ce, float gd, float* wfin,
                                      int rowbase, int d, int jg)
{
  float acc[RPB];
#pragma unroll
  for (int r = 0; r < RPB; ++r) acc[r] = 0.f;
#pragma unroll
  for (int seg = 0; seg < 4; ++seg){
    const int j0 = 8 * jg + 512 * seg;
    float2 u01 = aload2(&V[d * N_TRAIN + j0]);
    float2 u23 = aload2(&V[d * N_TRAIN + j0 + 2]);
    float2 u45 = aload2(&V[d * N_TRAIN + j0 + 4]);
    float2 u67 = aload2(&V[d * N_TRAIN + j0 + 6]);
    float u[8] = {u01.x, u01.y, u23.x, u23.y, u45.x, u45.y, u67.x, u67.y};
#pragma unroll
    for (int r = 0; r < RPB; ++r){
      uint4 sp = *reinterpret_cast<const uint4*>(&sqh[r * SQS + j0]);
      unsigned int w4[4] = {sp.x, sp.y, sp.z, sp.w};
#pragma unroll
      for (int e = 0; e < 4; ++e){
        __half2 h2 = *reinterpret_cast<const __half2*>(&w4[e]);
        float2 f2 = __half22float2(h2);
        acc[r] = fmaf(fexp2(ce * f2.x), u[2*e],   acc[r]);
        acc[r] = fmaf(fexp2(ce * f2.y), u[2*e+1], acc[r]);
      }
    }
  }
#pragma unroll
  for (int r = 0; r < RPB; ++r){
    acc[r] += __shfl_xor(acc[r], 1);
    acc[r] += __shfl_xor(acc[r], 2);
    acc[r] += __shfl_xor(acc[r], 4);
    acc[r] += __shfl_xor(acc[r], 8);
    acc[r] += __shfl_xor(acc[r], 16);
    acc[r] += __shfl_xor(acc[r], 32);
  }
  if (jg == 0){
#pragma unroll
    for (int r = 0; r < RPB; ++r){
      float ud = aload(&V[d * N_TRAIN + rowbase + r]);
      wfin[r * 16 + d] = gd * (acc[r] - ud);   // subtract diagonal (sq=0 -> exp=1)
    }
  }
}

__global__ __launch_bounds__(NTHR, 1)
void gp_rollout_kernel(const float* __restrict__ xtr, const float* __restrict__ ytr,
                       const float* __restrict__ ls,  const float* __restrict__ var,
                       const float* __restrict__ noi, const float* __restrict__ st0,
                       const float* __restrict__ act, const float* __restrict__ eps,
                       float* __restrict__ out, float* __restrict__ ws)
{
  cg::grid_group grid = cg::this_grid();
  const int tid = threadIdx.x;
  const int bid = blockIdx.x;
  const int rowbase = bid * RPB;

  float* PV0  = ws + OFF_PV0;
  float* PV1  = ws + OFF_PV1;
  float* AA0  = ws + OFF_AA0;
  float* AA1  = ws + OFF_AA1;
  float* ALPH = ws + OFF_AL;
  float* RES  = ws + OFF_RES;
  float* RES2 = ws + OFF_RES2;
  unsigned int* syn = (unsigned int*)(ws + OFF_SYN);

  __shared__ __half sqh[RPB * SQS];            // 32.9 KB
  __shared__ float act_s[HORIZON * DACT];      // 2 KB
  __shared__ float eps_s[HORIZON * DOUT];      // 4 KB
  __shared__ float pr[384];
  __shared__ float wfin[128];
  __shared__ float dsum[48];
  __shared__ float xcur[32];
  __shared__ float xrows[RPB * DIN];
  __shared__ float pv_s[128], v_s[128], yb_s[128];
  __shared__ float ce_s[16], g_s[16], s_s[16], var_s[16], nv_s[16];
  __shared__ float un_s[16], lam_s[16], sig_s[16], cb_s[16], ca_s[16];

  if (tid < 16){
    float l2 = ls[tid] * ls[tid];
    float nv = noi[tid] * noi[tid];
    float sd = var[tid] + nv + JITTER;
    ce_s[tid]  = -0.72134752044448f / l2;   // -0.5*log2(e)/ls^2
    g_s[tid]   = var[tid] / sd;
    s_s[tid]   = sd;
    var_s[tid] = var[tid];
    nv_s[tid]  = nv;
    un_s[tid]  = (float)N_TRAIN;            // ||ones||^2
  }
  if (tid < RPB * DIN) xrows[tid] = xtr[rowbase * DIN + tid];
  if (tid < HORIZON * DACT) act_s[tid] = act[tid];
  if (tid < HORIZON * DOUT) eps_s[tid] = eps[tid];
  __syncthreads();

  // -------- Phase 0: sq rows -> LDS fp16; caches; zero RES/RES2/syn ---------
  if (tid < 128){
    const int dd = tid >> 3, r = tid & 7;
    yb_s[tid] = ytr[(rowbase + r) * DOUT + dd] / s_s[dd];
    astore(&PV0[dd * N_TRAIN + rowbase + r], 1.0f);
    pv_s[tid] = 1.0f;
  }
  {
    const int r  = tid >> 7;      // 0..7, 128 threads per row
    const int c0 = tid & 127;
    float xl[DIN];
#pragma unroll
    for (int k = 0; k < DIN; ++k) xl[k] = xrows[r * DIN + k];
    for (int q = 0; q < 16; ++q){
      const int j = c0 + (q << 7);
      const float4* xp = reinterpret_cast<const float4*>(xtr + j * DIN);
      float sacc = 0.f;
#pragma unroll
      for (int v4 = 0; v4 < 6; ++v4){
        float4 x4 = xp[v4];
        float e0 = xl[v4*4+0] - x4.x, e1 = xl[v4*4+1] - x4.y;
        float e2 = xl[v4*4+2] - x4.z, e3 = xl[v4*4+3] - x4.w;
        sacc = fmaf(e0,e0, fmaf(e1,e1, fmaf(e2,e2, fmaf(e3,e3, sacc))));
      }
      sqh[r * SQS + j] = __float2half_rn(sacc);
    }
  }
  {
    int i = bid * NTHR + tid;
    if (i < MAXPC * 6144) RES[i] = 0.f;          // regular stores; grid.sync flushes
  }
  if (tid < 32) RES2[bid * 32 + tid] = 0.f;      // zero 64*64 (value,tag) pairs
  if (bid == 0 && tid < 512) syn[tid] = 0u;
  __syncthreads();
  __threadfence();
  grid.sync();            // single cooperative sync: init visibility everywhere
  int pc = 0;

  const int d  = tid >> 6;   // 0..15, one wave per output
  const int jg = tid & 63;
  const int lane8 = bid & 7;

  // -------- Power iteration (6) — r5 verbatim --------------------------------
  float* PVc = PV0; float* PVn = PV1;
#pragma unroll 1
  for (int it = 0; it < POWER_ITERS; ++it){
    const bool last = (it == POWER_ITERS - 1);
    sweep(sqh, PVc, ce_s[d], g_s[d], wfin, rowbase, d, jg);
    __syncthreads();
    if (tid < 128){
      const int dd = tid >> 3, r = tid & 7, rowg = rowbase + r;
      float w = wfin[r * 16 + dd];
      astore(&PVn[dd * N_TRAIN + rowg], w);
      float u = pv_s[tid];
      pv_s[tid] = w;
      pr[tid]       = w * w;
      pr[128 + tid] = u * w;
      pr[256 + tid] = last ? yb_s[tid] * w : 0.f;
    }
    __syncthreads();
    ++pc;
    if (tid < 48){
      const int slot = tid >> 4, dd = tid & 15;
      float s = 0.f;
#pragma unroll
      for (int r = 0; r < 8; ++r) s += pr[slot * 128 + dd * 8 + r];
      atomicAdd(&RES[pc * 6144 + (tid * 8 + lane8) * 16], s);
    }
    gbar_pre(syn, pc, true);
    if (tid < 48){
      const float* base = &RES[pc * 6144 + tid * 128];
      float s = 0.f;
#pragma unroll
      for (int l = 0; l < 8; ++l) s += aload(base + l * 16);
      dsum[tid] = s;
    }
    __syncthreads();
    if (tid < 16){
      float ww = dsum[tid];        // slot0: w.w
      float uw = dsum[16 + tid];   // slot1: u.w
      if (last){
        lam_s[tid] = uw / fmaxf(un_s[tid], 1e-30f);   // Rayleigh quotient
        float sg = rsqrtf(fmaxf(ww, 1e-38f));
        sig_s[tid] = sg;
        cb_s[tid]  = sg * dsum[32 + tid];              // v1^T (y/s)
      }
      un_s[tid] = ww;
    }
    __syncthreads();
    float* tmp = PVc; PVc = PVn; PVn = tmp;
  }

  // -------- a0 = b - cb*v1 ; analytically v^T a0 = 0 — r5 verbatim -----------
  if (tid < 128){
    const int dd = tid >> 3, r = tid & 7, rowg = rowbase + r;
    float v = sig_s[dd] * pv_s[tid];
    v_s[tid] = v;
    astore(&AA0[dd * N_TRAIN + rowg], yb_s[tid] - cb_s[dd] * v);
  }
  if (tid < 16) ca_s[tid] = 0.f;                 // v unit => v^T a0 = cb - cb = 0
  ++pc;
  gbar_pre(syn, pc, true);                       // visibility of AA0

  // -------- Richardson (10) on deflated operator — r5 verbatim ---------------
  float* Ac = AA0; float* An = AA1;
#pragma unroll 1
  for (int it = 0; it < RICH_ITERS; ++it){
    const bool last = (it == RICH_ITERS - 1);
    sweep(sqh, Ac, ce_s[d], g_s[d], wfin, rowbase, d, jg);
    __syncthreads();
    if (tid < 128){
      const int dd = tid >> 3, r = tid & 7, rowg = rowbase + r;
      float w = wfin[r * 16 + dd];
      float v = v_s[tid];
      float bperp = yb_s[tid] - cb_s[dd] * v;
      float anew = bperp - (w - lam_s[dd] * ca_s[dd] * v);
      if (last){
        astore(&ALPH[dd * N_TRAIN + rowg], anew + (cb_s[dd] / (1.f + lam_s[dd])) * v);
      } else {
        astore(&An[dd * N_TRAIN + rowg], anew);
        pr[tid] = v * anew;
      }
    }
    __syncthreads();
    ++pc;
    if (last){
      gbar_pre(syn, pc, bid < NROLL);   // blocks >= NROLL: arrive-only, exit
      if (bid >= NROLL) return;
      break;
    }
    if (tid < 16){
      float s = 0.f;
#pragma unroll
      for (int r = 0; r < 8; ++r) s += pr[tid * 8 + r];
      atomicAdd(&RES[pc * 6144 + (tid * 8 + lane8) * 16], s);
    }
    gbar_pre(syn, pc, true);
    if (tid < 16){
      const float* base = &RES[pc * 6144 + tid * 128];
      float s = 0.f;
#pragma unroll
      for (int l = 0; l < 8; ++l) s += aload(base + l * 16);
      ca_s[tid] = s;
    }
    __syncthreads();
    float* tmp = Ac; Ac = An; An = tmp;
  }

  // ======== Rollout: NROLL blocks; tag-in-payload sync; LDS epilogue =========
  const int dd_own = bid;
  const float ced = ce_s[dd_own], vd = var_s[dd_own];

  // fp32 alpha/v for this thread's two training points (registers)
  const int p0 = 2 * tid, p1 = 2 * tid + 1;
  float a0r = aload(&ALPH[dd_own * N_TRAIN + p0]);
  float a1r = aload(&ALPH[dd_own * N_TRAIN + p1]);
  float v0r = sig_s[dd_own] * aload(&PVc[dd_own * N_TRAIN + p0]);
  float v1r = sig_s[dd_own] * aload(&PVc[dd_own * N_TRAIN + p1]);

  float xp0[DIN], xp1[DIN];
#pragma unroll
  for (int k = 0; k < DIN; ++k){
    xp0[k] = xtr[p0 * DIN + k];
    xp1[k] = xtr[p1 * DIN + k];
  }
  if (tid < 16) xcur[tid] = st0[tid];
  __syncthreads();

#pragma unroll 1
  for (int t = 0; t < HORIZON; ++t){
    if (tid >= 16 && tid < 24) xcur[tid] = act_s[t * DACT + (tid - 16)];
    __syncthreads();
    // d2 + dots for this block's output (registers only)
    float sx = 0.f, sy = 0.f;
#pragma unroll
    for (int k = 0; k < DIN; ++k){
      float xc = xcur[k];
      float e0 = xc - xp0[k], e1 = xc - xp1[k];
      sx = fmaf(e0, e0, sx); sy = fmaf(e1, e1, sy);
    }
    float k0 = vd * fexp2(ced * sx);
    float k1 = vd * fexp2(ced * sy);
    float am = fmaf(k0, a0r, k1 * a1r);
    float ac = fmaf(k0, v0r, k1 * v1r);
    float ak = fmaf(k0, k0,  k1 * k1);
#pragma unroll
    for (int off = 1; off < 64; off <<= 1){
      am += __shfl_xor(am, off);
      ac += __shfl_xor(ac, off);
      ak += __shfl_xor(ak, off);
    }
    if ((tid & 63) == 0){
      const int wv = tid >> 6;
      pr[wv * 3 + 0] = am; pr[wv * 3 + 1] = ac; pr[wv * 3 + 2] = ak;
    }
    __syncthreads();
    // wave 0: publish tagged partials, poll all 48 (value travels WITH tag),
    // then hand results to LDS — NO shuffle from exec-masked lanes.
    if (tid < 64){
      const unsigned int want = (unsigned int)(t + 1);
      if (tid < 3){
        float s = 0.f;
#pragma unroll
        for (int w = 0; w < 16; ++w) s += pr[w * 3 + tid];
        float2 pv; pv.x = s;
        pv.y = __uint_as_float(want);
        astore2(&RES2[(t * 64 + dd_own * 3 + tid) * 2], pv);
      }
      float val = 0.f;
      {
        const float* base = &RES2[t * 128];
        while (true){
          float2 pv = (tid < 48) ? aload2(base + 2 * tid)
                                 : make_float2(0.f, __uint_as_float(want));
          if (__all(__float_as_uint(pv.y) == want)){ val = pv.x; break; }
          __builtin_amdgcn_s_sleep(1);
        }
      }
      if (tid < 48) dsum[tid] = val;   // all 48 source lanes ACTIVE here
    }
    __syncthreads();
    // r5's proven LDS-based epilogue, verbatim
    if (tid < 16){
      const int dd = tid;
      float mean = dsum[3*dd], c = dsum[3*dd+1], kk = dsum[3*dd+2];
      float lam = lam_s[dd];
      float qs = c * c / (1.f + lam) + (kk - c * c);   // k^T Ky^-1 k * s
      float q  = qs / s_s[dd];
      float pvv = var_s[dd] - q + nv_s[dd];
      float sd = sqrtf(fmaxf(pvv, 1e-12f));
      float ns = mean + sd * eps_s[t * DOUT + dd];
      xcur[dd] = ns;                     // identical in every block
      float rs = ns, cs = ns * ns;
      rs += __shfl_down(rs, 8);  cs += __shfl_down(cs, 8);
      rs += __shfl_down(rs, 4);  cs += __shfl_down(cs, 4);
      rs += __shfl_down(rs, 2);  cs += __shfl_down(cs, 2);
      rs += __shfl_down(rs, 1);  cs += __shfl_down(cs, 1);
      if (bid == 0){
        out[t * DOUT + dd]        = ns;     // trajectory
        out[1152 + t * DOUT + dd] = mean;   // means
        out[2176 + t * DOUT + dd] = sd;     // stds
        if (dd == 0){ out[1024 + t] = rs; out[1088 + t] = cs; }  // reward, cost
      }
    }
    __syncthreads();
  }
}

extern "C" void kernel_launch(void* const* d_in, const int* in_sizes, int n_in,
                              void* d_out, int out_size, void* d_ws, size_t ws_size,
                              hipStream_t stream) {
  (void)in_sizes; (void)n_in; (void)out_size; (void)ws_size;
  const float* xtr = (const float*)d_in[0];
  const float* ytr = (const float*)d_in[1];
  const float* ls  = (const float*)d_in[2];
  const float* var = (const float*)d_in[3];
  const float* noi = (const float*)d_in[4];
  const float* st0 = (const float*)d_in[5];
  const float* act = (const float*)d_in[6];
  const float* eps = (const float*)d_in[7];
  float* out = (float*)d_out;
  float* ws  = (float*)d_ws;
  void* args[] = { &xtr, &ytr, &ls, &var, &noi, &st0, &act, &eps, &out, &ws };
  hipLaunchCooperativeKernel((const void*)gp_rollout_kernel,
                             dim3(NBLK), dim3(NTHR), args, 0, stream);
}